// Round 11
// baseline (97.055 us; speedup 1.0000x reference)
//
#include <hip/hip_runtime.h>
#include <hip/hip_bf16.h>

#define NOBJ 21

typedef __bf16 bf16x8 __attribute__((ext_vector_type(8)));
typedef float f32x16 __attribute__((ext_vector_type(16)));
typedef float f32x4  __attribute__((ext_vector_type(4)));

__device__ __forceinline__ float ftanh(float x) {
    // tanh(x) = 1 - 2/(exp2(x*2*log2e)+1); one mul folded, native v_exp_f32.
    float e = __builtin_amdgcn_exp2f(x * 2.8853900817779268f);
    float r = __builtin_amdgcn_rcpf(e + 1.0f);
    return __builtin_fmaf(-2.0f, r, 1.0f);
}

// ---------------- workspace layout ----------------
// fe3 @0 (1024) | w2s @1024 (32768) | wdt @33792 (49152) | wbt @82944 (49152)
// wst @132096 (32768) | wat @164864 (32768)   total 197632
// w2s: Wm2 in 16x16x32 B-frag layout: fi=(nt*4+kf)*64+lane,
//      elem e = Wm2[kf*32+(lane>>4)*8+e][nt*16+(lane&15)]
// wdt/wbt/wst/wat: 32x32x16 B-frag layout (verified in-kernel):
//      col n = ct*32+(lane&31), k = ks*16+(lane>>5)*8+e
__global__ void setup_kernel(const float* __restrict__ emb, const float* __restrict__ We,
                             const float* __restrict__ be, const float* __restrict__ Wm2,
                             const float* __restrict__ Wm1, const float* __restrict__ Ws2,
                             const float* __restrict__ Wa1,
                             float* __restrict__ fe3, __bf16* __restrict__ w2s,
                             __bf16* __restrict__ wdt, __bf16* __restrict__ wbt,
                             __bf16* __restrict__ wst, __bf16* __restrict__ wat,
                             int level) {
    int t = threadIdx.x;
    if (blockIdx.x == 48) {
        if (t < 192) {
            int cc = t >> 6, e = t & 63;
            float acc = be[e];
            for (int k = 0; k < 64; ++k)
                acc += ftanh(emb[cc * 64 + k]) * We[k * 64 + e];
            fe3[t] = ftanh(acc);
        }
        return;
    }
    int fid = blockIdx.x * 256 + t;   // 0..12287
    if (fid < 2048) {                 // w2s: 16x16 frags (K=128 -> kf 0..3, nt 0..7)
        if (level < 1) return;
        int nt = fid >> 8, kf = (fid >> 6) & 3, ln = fid & 63;
        int n  = nt * 16 + (ln & 15);
        int k0 = kf * 32 + ((ln >> 4) & 3) * 8;
        bf16x8 v;
        #pragma unroll
        for (int e = 0; e < 8; ++e) v[e] = (__bf16)Wm2[(k0 + e) * 128 + n];
        *reinterpret_cast<bf16x8*>(&w2s[fid * 8]) = v;
    } else if (fid < 5120) {          // wdt (K=192)
        if (level < 1) return;
        int q = fid - 2048;
        int ct = q / 768, r = q % 768, ks = r >> 6, ln = r & 63;
        int n = ct * 32 + (ln & 31), k0 = ks * 16 + (ln >> 5) * 8;
        bf16x8 v;
        #pragma unroll
        for (int e = 0; e < 8; ++e)
            v[e] = (__bf16)(Wm1[(k0 + e) * 128 + n] - Wm1[(192 + k0 + e) * 128 + n]);
        *reinterpret_cast<bf16x8*>(&wdt[q * 8]) = v;
    } else if (fid < 8192) {          // wbt (K=192)
        if (level < 1) return;
        int q = fid - 5120;
        int ct = q / 768, r = q % 768, ks = r >> 6, ln = r & 63;
        int n = ct * 32 + (ln & 31), k0 = ks * 16 + (ln >> 5) * 8;
        bf16x8 v;
        #pragma unroll
        for (int e = 0; e < 8; ++e) v[e] = (__bf16)Wm1[(192 + k0 + e) * 128 + n];
        *reinterpret_cast<bf16x8*>(&wbt[q * 8]) = v;
    } else if (fid < 10240) {         // wst (K=128)
        if (level < 2) return;
        int q = fid - 8192;
        int ct = q >> 9, ks = (q >> 6) & 7, ln = q & 63;
        int n = ct * 32 + (ln & 31), k0 = ks * 16 + (ln >> 5) * 8;
        bf16x8 v;
        #pragma unroll
        for (int e = 0; e < 8; ++e) v[e] = (__bf16)Ws2[(k0 + e) * 128 + n];
        *reinterpret_cast<bf16x8*>(&wst[q * 8]) = v;
    } else {                          // wat (K=128)
        if (level < 2) return;
        int q = fid - 10240;
        int ct = q >> 9, ks = (q >> 6) & 7, ln = q & 63;
        int n = ct * 32 + (ln & 31), k0 = ks * 16 + (ln >> 5) * 8;
        bf16x8 v;
        #pragma unroll
        for (int e = 0; e < 8; ++e) v[e] = (__bf16)Wa1[(k0 + e) * 128 + n];
        *reinterpret_cast<bf16x8*>(&wat[q * 8]) = v;
    }
}

// f32 LDS 16B-chunk XOR swizzle (row-major [*][128] f32)
__device__ __forceinline__ int uvswz(int row, int k) {
    return row * 128 + (((k >> 2) ^ (row & 15)) << 2) + (k & 3);
}
// bf16 LDS 16B-chunk XOR swizzle (row-major [*][128] bf16)
__device__ __forceinline__ int bswz(int row, int k) {
    return row * 128 + (((k >> 3) ^ (row & 15)) << 3) + (k & 7);
}

// LDS layout (40448 B):
//   @0     hL bf16 swz [32][128] (steps1-2) | overlay: uL f32 swz [21][128] (step3+),
//          then a1L f32 [21][128] (phase3+)
//   @10752 vL f32 swz [21][128] | overlay: spl f32[84]+cat int[21] (steps 0-1)
//   @21504 fL bf16 swz [21][256] 10752
//   @32256 xL bf16 swz [32][128] 8192
#define SMEM_SZ 40448

template<int WS>
__global__ __launch_bounds__(512, 2)
void actor_kernel(const float* __restrict__ state, const float* __restrict__ ts,
                  const float* __restrict__ Ws1, const float* __restrict__ bs1,
                  const float* __restrict__ Ws2, const float* __restrict__ bs2,
                  const float* __restrict__ Wm1, const float* __restrict__ bm1,
                  const float* __restrict__ Wm2, const float* __restrict__ bm2,
                  const float* __restrict__ Wa1, const float* __restrict__ ba1,
                  const float* __restrict__ Wa2, const float* __restrict__ ba2,
                  const float* __restrict__ fe3, const __bf16* __restrict__ w2s,
                  const __bf16* __restrict__ wdt, const __bf16* __restrict__ wbt,
                  const __bf16* __restrict__ wst, const __bf16* __restrict__ wat,
                  float* __restrict__ out) {
    __shared__ __align__(16) unsigned char smem[SMEM_SZ];
    __bf16* hL  = (__bf16*)(smem);
    float*  uL  = (float*)(smem);
    float*  a1L = (float*)(smem);
    float*  vL  = (float*)(smem + 10752);
    float*  spl = (float*)(smem + 10752);
    int*    catl= (int*)(smem + 10752 + 336);
    __bf16* fL  = (__bf16*)(smem + 21504);
    __bf16* xL  = (__bf16*)(smem + 32256);

    const int b   = blockIdx.x;
    const int tid = threadIdx.x;
    const int c   = tid & 127;
    const int grp = tid >> 7;        // 0..3 (128-thread groups)
    const int lane = tid & 63;
    const int wave = tid >> 6;       // 0..7
    const int rowA = lane & 31;
    const int hi   = lane >> 5;

    // ---- step 0 ----
    if (tid < NOBJ * 4) {
        int i = tid >> 2, m = tid & 3;
        float v;
        if (m < 2) v = state[b * 63 + i * 3 + m];
        else       v = ftanh(ts[(b * NOBJ + i) * 2 + (m - 2)]);
        spl[tid] = v;
    }
    if (tid >= 128 && tid < 128 + NOBJ) {
        int i = tid - 128;
        catl[i] = (int)state[b * 63 + i * 3 + 2];
    }
    __syncthreads();

    // ---- step 1: h = tanh(sp @ Ws1 + bs1) -> swizzled bf16 hL (rows split 4 ways) ----
    {
        float b1 = bs1[c];
        float w0 = Ws1[0 * 128 + c], w1 = Ws1[1 * 128 + c];
        float w2 = Ws1[2 * 128 + c], w3 = Ws1[3 * 128 + c];
        for (int i = grp; i < NOBJ; i += 4) {
            float acc = b1 + spl[i*4+0]*w0 + spl[i*4+1]*w1 + spl[i*4+2]*w2 + spl[i*4+3]*w3;
            hL[bswz(i, c)] = (__bf16)ftanh(acc);
        }
    }
    __syncthreads();

    // ---- step 2: f[:, :128] = tanh(h @ Ws2 + bs2) -> swizzled bf16 fL ----
    if constexpr (WS == 2) {
        if (wave < 4) {
            const int cN = wave * 32 + rowA;
            f32x16 accS;
            #pragma unroll
            for (int r = 0; r < 16; ++r) accS[r] = 0.f;
            #pragma unroll
            for (int ks = 0; ks < 8; ++ks) {
                int ch = 2 * ks + hi;
                bf16x8 a = *(const bf16x8*)&hL[rowA * 128 + ((ch ^ (rowA & 15)) << 3)];
                bf16x8 bb = *(const bf16x8*)&wst[((wave * 8 + ks) * 64 + lane) * 8];
                accS = __builtin_amdgcn_mfma_f32_32x32x16_bf16(a, bb, accS, 0, 0, 0);
            }
            float b2 = bs2[cN];
            #pragma unroll
            for (int r = 0; r < 16; ++r) {
                int j = (r & 3) + 8 * (r >> 2) + 4 * hi;
                if (j < NOBJ)
                    fL[j * 256 + (((cN >> 3) ^ (j & 15)) << 3) + (cN & 7)] = (__bf16)ftanh(accS[r] + b2);
            }
        }
    } else {
        float acc[6];
        #pragma unroll
        for (int gi = 0; gi < 6; ++gi) acc[gi] = 0.f;
        const unsigned int* hrow = (const unsigned int*)hL;
        for (int k2 = 0; k2 < 64; ++k2) {
            float w0 = Ws2[(2 * k2) * 128 + c];
            float w1 = Ws2[(2 * k2 + 1) * 128 + c];
            #pragma unroll
            for (int gi = 0; gi < 6; ++gi) {
                int i = grp + 4 * gi;
                if (i < NOBJ) {
                    unsigned int pr = hrow[i * 64 + (((k2 >> 2) ^ (i & 15)) << 2) + (k2 & 3)];
                    float lo = __uint_as_float(pr << 16);
                    float hh = __uint_as_float(pr & 0xffff0000u);
                    acc[gi] = __builtin_fmaf(hh, w1, __builtin_fmaf(lo, w0, acc[gi]));
                }
            }
        }
        float b2 = bs2[c];
        #pragma unroll
        for (int gi = 0; gi < 6; ++gi) {
            int i = grp + 4 * gi;
            if (i < NOBJ)
                fL[i * 256 + (((c >> 3) ^ (i & 15)) << 3) + (c & 7)] = (__bf16)ftanh(acc[gi] + b2);
        }
    }
    for (int idx = tid; idx < NOBJ * 64; idx += 512) {
        int i = idx >> 6, e = idx & 63;
        fL[i * 256 + ((((16 + (e >> 3)) ^ (i & 15))) << 3) + (e & 7)] = (__bf16)fe3[catl[i] * 64 + e];
    }
    __syncthreads();

    // ---- step 3: u = f@Wd + bm1 (waves 0-3) ; v = f@Wb (waves 4-7) ----
    if constexpr (WS >= 1) {
        const int ct = wave & 3;
        const int cN = ct * 32 + rowA;
        const int jcA = rowA < NOBJ ? rowA : NOBJ - 1;
        const __bf16* wt = (wave < 4) ? wdt : wbt;
        f32x16 acc;
        #pragma unroll
        for (int r = 0; r < 16; ++r) acc[r] = 0.f;
        #pragma unroll
        for (int ks = 0; ks < 12; ++ks) {
            int ch = 2 * ks + hi;
            bf16x8 a = *(const bf16x8*)&fL[jcA * 256 + ((ch ^ (jcA & 15)) << 3)];
            bf16x8 bw = *(const bf16x8*)&wt[((ct * 12 + ks) * 64 + lane) * 8];
            acc = __builtin_amdgcn_mfma_f32_32x32x16_bf16(a, bw, acc, 0, 0, 0);
        }
        float b1 = (wave < 4) ? bm1[cN] : 0.f;
        float* dst = (wave < 4) ? uL : vL;
        #pragma unroll
        for (int r = 0; r < 16; ++r) {
            int j = (r & 3) + 8 * (r >> 2) + 4 * hi;
            if (j < NOBJ) dst[uvswz(j, cN)] = acc[r] + b1;
        }
    } else {
        float ua[6], va[6];
        #pragma unroll
        for (int gi = 0; gi < 6; ++gi) { ua[gi] = 0.f; va[gi] = 0.f; }
        const unsigned int* frow = (const unsigned int*)fL;   // row stride 128 dwords
        for (int k2 = 0; k2 < 96; ++k2) {
            int k = 2 * k2;
            float wt0 = Wm1[k * 128 + c],         wt1 = Wm1[(k + 1) * 128 + c];
            float wb0 = Wm1[(192 + k) * 128 + c], wb1 = Wm1[(193 + k) * 128 + c];
            float wd0 = wt0 - wb0, wd1 = wt1 - wb1;
            #pragma unroll
            for (int gi = 0; gi < 6; ++gi) {
                int i = grp + 4 * gi;
                if (i < NOBJ) {
                    unsigned int pr = frow[i * 128 + (((k2 >> 2) ^ (i & 15)) << 2) + (k2 & 3)];
                    float lo = __uint_as_float(pr << 16);
                    float hh = __uint_as_float(pr & 0xffff0000u);
                    ua[gi] = __builtin_fmaf(hh, wd1, __builtin_fmaf(lo, wd0, ua[gi]));
                    va[gi] = __builtin_fmaf(hh, wb1, __builtin_fmaf(lo, wb0, va[gi]));
                }
            }
        }
        float b1 = bm1[c];
        #pragma unroll
        for (int gi = 0; gi < 6; ++gi) {
            int i = grp + 4 * gi;
            if (i < NOBJ) {
                uL[uvswz(i, c)] = ua[gi] + b1;
                vL[uvswz(i, c)] = va[gi];
            }
        }
    }
    __syncthreads();

    // ---- phase 2: 16x16x32 MFMA, A built once per i, i strided by 8 waves ----
    const int l15 = lane & 15;
    const int l4  = (lane >> 4) & 3;
    const int j1c = (16 + l15) < NOBJ ? (16 + l15) : NOBJ - 1;
    float bm2v[8];
    #pragma unroll
    for (int nt = 0; nt < 8; ++nt) bm2v[nt] = bm2[nt * 16 + l15];

    for (int i = wave; i < NOBJ; i += 8) {
        // A-frags: A0 = rows j=l15 (tile0), A1 = rows j=16+l15 (tile1, clamped)
        // k = kf*32 + l4*8 + e
        bf16x8 A0[4], A1[4];
        #pragma unroll
        for (int kf = 0; kf < 4; ++kf) {
            int c0 = kf * 8 + l4 * 2;
            f32x4 u0  = *(const f32x4*)&uL[i * 128 + (((c0)     ^ (i & 15)) << 2)];
            f32x4 u1  = *(const f32x4*)&uL[i * 128 + (((c0 + 1) ^ (i & 15)) << 2)];
            f32x4 va0 = *(const f32x4*)&vL[l15 * 128 + (((c0)     ^ l15) << 2)];
            f32x4 va1 = *(const f32x4*)&vL[l15 * 128 + (((c0 + 1) ^ l15) << 2)];
            f32x4 vb0 = *(const f32x4*)&vL[j1c * 128 + (((c0)     ^ (j1c & 15)) << 2)];
            f32x4 vb1 = *(const f32x4*)&vL[j1c * 128 + (((c0 + 1) ^ (j1c & 15)) << 2)];
            bf16x8 a0f, a1f;
            #pragma unroll
            for (int e = 0; e < 4; ++e) {
                a0f[e]     = (__bf16)ftanh(u0[e] + va0[e]);
                a0f[4 + e] = (__bf16)ftanh(u1[e] + va1[e]);
                a1f[e]     = (__bf16)ftanh(u0[e] + vb0[e]);
                a1f[4 + e] = (__bf16)ftanh(u1[e] + vb1[e]);
            }
            A0[kf] = a0f; A1[kf] = a1f;
        }
        #pragma unroll
        for (int nt = 0; nt < 8; ++nt) {
            f32x4 c0a, c1a;
            #pragma unroll
            for (int r = 0; r < 4; ++r) { c0a[r] = 0.f; c1a[r] = 0.f; }
            #pragma unroll
            for (int kf = 0; kf < 4; ++kf) {
                bf16x8 bb;
                if constexpr (WS >= 1) {
                    bb = *(const bf16x8*)&w2s[((nt * 4 + kf) * 64 + lane) * 8];
                } else {
                    int k0 = kf * 32 + l4 * 8;
                    #pragma unroll
                    for (int e = 0; e < 8; ++e)
                        bb[e] = (__bf16)Wm2[(k0 + e) * 128 + nt * 16 + l15];
                }
                c0a = __builtin_amdgcn_mfma_f32_16x16x32_bf16(A0[kf], bb, c0a, 0, 0, 0);
                c1a = __builtin_amdgcn_mfma_f32_16x16x32_bf16(A1[kf], bb, c1a, 0, 0, 0);
            }
            // D layout 16x16: col = lane&15, row = (lane>>4)*4 + r
            float m = -INFINITY;
            #pragma unroll
            for (int r = 0; r < 4; ++r) {
                int j = l4 * 4 + r;
                if (j != i) m = fmaxf(m, c0a[r]);
            }
            #pragma unroll
            for (int r = 0; r < 4; ++r) {
                int j = 16 + l4 * 4 + r;
                if (j < NOBJ && j != i) m = fmaxf(m, c1a[r]);
            }
            m = fmaxf(m, __shfl_xor(m, 16));
            m = fmaxf(m, __shfl_xor(m, 32));
            if (lane < 16) xL[bswz(i, nt * 16 + l15)] = (__bf16)ftanh(m + bm2v[nt]);
        }
    }
    __syncthreads();

    // ---- phase 3: a1 = tanh(x @ Wa1 + ba1) -> f32 a1L (overlays uL) ----
    if constexpr (WS == 2) {
        f32x16 accP;
        #pragma unroll
        for (int r = 0; r < 16; ++r) accP[r] = 0.f;
        if (wave < 4) {
            #pragma unroll
            for (int ks = 0; ks < 8; ++ks) {
                int ch = 2 * ks + hi;
                bf16x8 a = *(const bf16x8*)&xL[rowA * 128 + ((ch ^ (rowA & 15)) << 3)];
                bf16x8 bb = *(const bf16x8*)&wat[((wave * 8 + ks) * 64 + lane) * 8];
                accP = __builtin_amdgcn_mfma_f32_32x32x16_bf16(a, bb, accP, 0, 0, 0);
            }
        }
        __syncthreads();   // all uL/xL readers done before a1L overlay write
        if (wave < 4) {
            const int cN = wave * 32 + rowA;
            float b1 = ba1[cN];
            #pragma unroll
            for (int r = 0; r < 16; ++r) {
                int j = (r & 3) + 8 * (r >> 2) + 4 * hi;
                if (j < NOBJ) a1L[j * 128 + cN] = ftanh(accP[r] + b1);
            }
        }
    } else {
        float acc[6];
        #pragma unroll
        for (int gi = 0; gi < 6; ++gi) acc[gi] = 0.f;
        const unsigned int* xrow = (const unsigned int*)xL;
        for (int k2 = 0; k2 < 64; ++k2) {
            float w0 = Wa1[(2 * k2) * 128 + c];
            float w1 = Wa1[(2 * k2 + 1) * 128 + c];
            #pragma unroll
            for (int gi = 0; gi < 6; ++gi) {
                int i = grp + 4 * gi;
                if (i < NOBJ) {
                    unsigned int pr = xrow[i * 64 + (((k2 >> 2) ^ (i & 15)) << 2) + (k2 & 3)];
                    float lo = __uint_as_float(pr << 16);
                    float hh = __uint_as_float(pr & 0xffff0000u);
                    acc[gi] = __builtin_fmaf(hh, w1, __builtin_fmaf(lo, w0, acc[gi]));
                }
            }
        }
        float b1 = ba1[c];
        __syncthreads();
        #pragma unroll
        for (int gi = 0; gi < 6; ++gi) {
            int i = grp + 4 * gi;
            if (i < NOBJ) a1L[i * 128 + c] = ftanh(acc[gi] + b1);
        }
    }
    __syncthreads();

    // ---- head: 4 ILP accumulators, f32x4 reads, i-rotated to spread banks ----
    if (tid < NOBJ * 4) {
        int i = tid >> 2, o = tid & 3;
        float ac0 = ba2[o], ac1 = 0.f, ac2 = 0.f, ac3 = 0.f;
        for (int k4 = 0; k4 < 32; ++k4) {
            int kr = (k4 + i) & 31;
            f32x4 av = *(const f32x4*)&a1L[i * 128 + kr * 4];
            ac0 = __builtin_fmaf(av[0], Wa2[(kr * 4 + 0) * 4 + o], ac0);
            ac1 = __builtin_fmaf(av[1], Wa2[(kr * 4 + 1) * 4 + o], ac1);
            ac2 = __builtin_fmaf(av[2], Wa2[(kr * 4 + 2) * 4 + o], ac2);
            ac3 = __builtin_fmaf(av[3], Wa2[(kr * 4 + 3) * 4 + o], ac3);
        }
        float acc = (ac0 + ac1) + (ac2 + ac3);
        if (o < 2) {
            out[b * 42 + i * 2 + o] = 0.3f * ftanh(acc);
        } else {
            float t   = ftanh(acc);
            float lsv = -5.0f + 3.5f * (t + 1.0f);
            out[43008 + b * 42 + i * 2 + (o - 2)] = __expf(lsv);
        }
    }
}

extern "C" void kernel_launch(void* const* d_in, const int* in_sizes, int n_in,
                              void* d_out, int out_size, void* d_ws, size_t ws_size,
                              hipStream_t stream) {
    (void)in_sizes; (void)n_in; (void)out_size;
    const float* state = (const float*)d_in[0];
    const float* ts    = (const float*)d_in[1];
    const float* emb   = (const float*)d_in[2];
    const float* We    = (const float*)d_in[3];
    const float* be    = (const float*)d_in[4];
    const float* Ws1   = (const float*)d_in[5];
    const float* bs1   = (const float*)d_in[6];
    const float* Ws2   = (const float*)d_in[7];
    const float* bs2   = (const float*)d_in[8];
    const float* Wm1   = (const float*)d_in[9];
    const float* bm1   = (const float*)d_in[10];
    const float* Wm2   = (const float*)d_in[11];
    const float* bm2   = (const float*)d_in[12];
    const float* Wa1   = (const float*)d_in[13];
    const float* ba1   = (const float*)d_in[14];
    const float* Wa2   = (const float*)d_in[15];
    const float* ba2   = (const float*)d_in[16];
    float* outp = (float*)d_out;

    float*  fe3 = (float*)d_ws;
    __bf16* w2s = (__bf16*)((char*)d_ws + 1024);
    __bf16* wdt = (__bf16*)((char*)d_ws + 33792);
    __bf16* wbt = (__bf16*)((char*)d_ws + 82944);
    __bf16* wst = (__bf16*)((char*)d_ws + 132096);
    __bf16* wat = (__bf16*)((char*)d_ws + 164864);
    const size_t need1 = 132096, need2 = 197632;
    const int level = (ws_size >= need2) ? 2 : ((ws_size >= need1) ? 1 : 0);

    setup_kernel<<<dim3(49), dim3(256), 0, stream>>>(emb, We, be, Wm2, Wm1, Ws2, Wa1,
                                                     fe3, w2s, wdt, wbt, wst, wat, level);
    if (level == 2)
        actor_kernel<2><<<dim3(1024), dim3(512), 0, stream>>>(
            state, ts, Ws1, bs1, Ws2, bs2, Wm1, bm1, Wm2, bm2,
            Wa1, ba1, Wa2, ba2, fe3, w2s, wdt, wbt, wst, wat, outp);
    else if (level == 1)
        actor_kernel<1><<<dim3(1024), dim3(512), 0, stream>>>(
            state, ts, Ws1, bs1, Ws2, bs2, Wm1, bm1, Wm2, bm2,
            Wa1, ba1, Wa2, ba2, fe3, w2s, wdt, wbt, wst, wat, outp);
    else
        actor_kernel<0><<<dim3(1024), dim3(512), 0, stream>>>(
            state, ts, Ws1, bs1, Ws2, bs2, Wm1, bm1, Wm2, bm2,
            Wa1, ba1, Wa2, ba2, fe3, w2s, wdt, wbt, wst, wat, outp);
}

// Round 12
// 91.119 us; speedup vs baseline: 1.0651x; 1.0651x over previous
//
#include <hip/hip_runtime.h>
#include <hip/hip_bf16.h>

#define NOBJ 21

typedef __bf16 bf16x8 __attribute__((ext_vector_type(8)));
typedef float f32x16 __attribute__((ext_vector_type(16)));
typedef float f32x4  __attribute__((ext_vector_type(4)));

#define PRESCALE 2.8853900817779268f   // 2*log2(e)

__device__ __forceinline__ float ftanh(float x) {
    // tanh(x) = 1 - 2/(exp2(x*2*log2e)+1)
    float e = __builtin_amdgcn_exp2f(x * PRESCALE);
    float r = __builtin_amdgcn_rcpf(e + 1.0f);
    return __builtin_fmaf(-2.0f, r, 1.0f);
}
__device__ __forceinline__ float ftanh_pre(float xp) {
    // xp already scaled by PRESCALE
    float e = __builtin_amdgcn_exp2f(xp);
    float r = __builtin_amdgcn_rcpf(e + 1.0f);
    return __builtin_fmaf(-2.0f, r, 1.0f);
}

// ---------------- workspace layout ----------------
// fe3 @0 (1024) | w2s @1024 (32768) | wdt @33792 (49152) | wbt @82944 (49152)
// wst @132096 (32768) | wat @164864 (32768)   total 197632
// w2s: Wm2 in 16x16x32 B-frag layout: fi=(nt*4+kf)*64+lane,
//      elem e = Wm2[kf*32+(lane>>4)*8+e][nt*16+(lane&15)]
// wdt/wbt/wst/wat: 32x32x16 B-frag layout (verified in-kernel):
//      col n = ct*32+(lane&31), k = ks*16+(lane>>5)*8+e
__global__ void setup_kernel(const float* __restrict__ emb, const float* __restrict__ We,
                             const float* __restrict__ be, const float* __restrict__ Wm2,
                             const float* __restrict__ Wm1, const float* __restrict__ Ws2,
                             const float* __restrict__ Wa1,
                             float* __restrict__ fe3, __bf16* __restrict__ w2s,
                             __bf16* __restrict__ wdt, __bf16* __restrict__ wbt,
                             __bf16* __restrict__ wst, __bf16* __restrict__ wat,
                             int level) {
    int t = threadIdx.x;
    if (blockIdx.x == 48) {
        if (t < 192) {
            int cc = t >> 6, e = t & 63;
            float acc = be[e];
            for (int k = 0; k < 64; ++k)
                acc += ftanh(emb[cc * 64 + k]) * We[k * 64 + e];
            fe3[t] = ftanh(acc);
        }
        return;
    }
    int fid = blockIdx.x * 256 + t;   // 0..12287
    if (fid < 2048) {                 // w2s: 16x16 frags (K=128 -> kf 0..3, nt 0..7)
        if (level < 1) return;
        int nt = fid >> 8, kf = (fid >> 6) & 3, ln = fid & 63;
        int n  = nt * 16 + (ln & 15);
        int k0 = kf * 32 + ((ln >> 4) & 3) * 8;
        bf16x8 v;
        #pragma unroll
        for (int e = 0; e < 8; ++e) v[e] = (__bf16)Wm2[(k0 + e) * 128 + n];
        *reinterpret_cast<bf16x8*>(&w2s[fid * 8]) = v;
    } else if (fid < 5120) {          // wdt (K=192)
        if (level < 1) return;
        int q = fid - 2048;
        int ct = q / 768, r = q % 768, ks = r >> 6, ln = r & 63;
        int n = ct * 32 + (ln & 31), k0 = ks * 16 + (ln >> 5) * 8;
        bf16x8 v;
        #pragma unroll
        for (int e = 0; e < 8; ++e)
            v[e] = (__bf16)(Wm1[(k0 + e) * 128 + n] - Wm1[(192 + k0 + e) * 128 + n]);
        *reinterpret_cast<bf16x8*>(&wdt[q * 8]) = v;
    } else if (fid < 8192) {          // wbt (K=192)
        if (level < 1) return;
        int q = fid - 5120;
        int ct = q / 768, r = q % 768, ks = r >> 6, ln = r & 63;
        int n = ct * 32 + (ln & 31), k0 = ks * 16 + (ln >> 5) * 8;
        bf16x8 v;
        #pragma unroll
        for (int e = 0; e < 8; ++e) v[e] = (__bf16)Wm1[(192 + k0 + e) * 128 + n];
        *reinterpret_cast<bf16x8*>(&wbt[q * 8]) = v;
    } else if (fid < 10240) {         // wst (K=128)
        if (level < 2) return;
        int q = fid - 8192;
        int ct = q >> 9, ks = (q >> 6) & 7, ln = q & 63;
        int n = ct * 32 + (ln & 31), k0 = ks * 16 + (ln >> 5) * 8;
        bf16x8 v;
        #pragma unroll
        for (int e = 0; e < 8; ++e) v[e] = (__bf16)Ws2[(k0 + e) * 128 + n];
        *reinterpret_cast<bf16x8*>(&wst[q * 8]) = v;
    } else {                          // wat (K=128)
        if (level < 2) return;
        int q = fid - 10240;
        int ct = q >> 9, ks = (q >> 6) & 7, ln = q & 63;
        int n = ct * 32 + (ln & 31), k0 = ks * 16 + (ln >> 5) * 8;
        bf16x8 v;
        #pragma unroll
        for (int e = 0; e < 8; ++e) v[e] = (__bf16)Wa1[(k0 + e) * 128 + n];
        *reinterpret_cast<bf16x8*>(&wat[q * 8]) = v;
    }
}

// f32 LDS 16B-chunk XOR swizzle (row-major [*][128] f32)
__device__ __forceinline__ int uvswz(int row, int k) {
    return row * 128 + (((k >> 2) ^ (row & 15)) << 2) + (k & 3);
}
// bf16 LDS 16B-chunk XOR swizzle (row-major [*][128] bf16)
__device__ __forceinline__ int bswz(int row, int k) {
    return row * 128 + (((k >> 3) ^ (row & 15)) << 3) + (k & 7);
}

// LDS layout (40448 B):
//   @0     hL bf16 swz [32][128] (steps1-2) | overlay: uL f32 swz [21][128] (step3+),
//          then a1L f32 [21][128] (phase3+)
//   @10752 vL f32 swz [21][128] | overlay: spl f32[84]+cat int[21] (steps 0-1)
//   @21504 fL bf16 swz [21][256] 10752
//   @32256 xL bf16 swz [32][128] 8192
// NOTE: uL/vL hold PRE-SCALED (×2log2e) values; consumed only by phase-2 tanh.
#define SMEM_SZ 40448

template<int WS>
__global__ __launch_bounds__(256, 2)
void actor_kernel(const float* __restrict__ state, const float* __restrict__ ts,
                  const float* __restrict__ Ws1, const float* __restrict__ bs1,
                  const float* __restrict__ Ws2, const float* __restrict__ bs2,
                  const float* __restrict__ Wm1, const float* __restrict__ bm1,
                  const float* __restrict__ Wm2, const float* __restrict__ bm2,
                  const float* __restrict__ Wa1, const float* __restrict__ ba1,
                  const float* __restrict__ Wa2, const float* __restrict__ ba2,
                  const float* __restrict__ fe3, const __bf16* __restrict__ w2s,
                  const __bf16* __restrict__ wdt, const __bf16* __restrict__ wbt,
                  const __bf16* __restrict__ wst, const __bf16* __restrict__ wat,
                  float* __restrict__ out) {
    __shared__ __align__(16) unsigned char smem[SMEM_SZ];
    __bf16* hL  = (__bf16*)(smem);
    float*  uL  = (float*)(smem);
    float*  a1L = (float*)(smem);
    float*  vL  = (float*)(smem + 10752);
    float*  spl = (float*)(smem + 10752);
    int*    catl= (int*)(smem + 10752 + 336);
    __bf16* fL  = (__bf16*)(smem + 21504);
    __bf16* xL  = (__bf16*)(smem + 32256);

    const int b   = blockIdx.x;
    const int tid = threadIdx.x;
    const int c   = tid & 127;
    const int half= tid >> 7;
    const int i0  = half ? 11 : 0;
    const int NI  = half ? (NOBJ - 11) : 11;
    const int lane = tid & 63;
    const int wave = tid >> 6;
    const int rowA = lane & 31;
    const int hi   = lane >> 5;

    // ---- step 0 ----
    if (tid < NOBJ * 4) {
        int i = tid >> 2, m = tid & 3;
        float v;
        if (m < 2) v = state[b * 63 + i * 3 + m];
        else       v = ftanh(ts[(b * NOBJ + i) * 2 + (m - 2)]);
        spl[tid] = v;
    }
    if (tid >= 128 && tid < 128 + NOBJ) {
        int i = tid - 128;
        catl[i] = (int)state[b * 63 + i * 3 + 2];
    }
    __syncthreads();

    // ---- step 1: h = tanh(sp @ Ws1 + bs1) -> swizzled bf16 hL ----
    {
        float b1 = bs1[c];
        float w0 = Ws1[0 * 128 + c], w1 = Ws1[1 * 128 + c];
        float w2 = Ws1[2 * 128 + c], w3 = Ws1[3 * 128 + c];
        for (int g = 0; g < NI; ++g) {
            int i = i0 + g;
            float acc = b1 + spl[i*4+0]*w0 + spl[i*4+1]*w1 + spl[i*4+2]*w2 + spl[i*4+3]*w3;
            hL[bswz(i, c)] = (__bf16)ftanh(acc);
        }
    }
    __syncthreads();

    // ---- step 2: f[:, :128] = tanh(h @ Ws2 + bs2) -> swizzled bf16 fL ----
    if constexpr (WS == 2) {
        const int cN = wave * 32 + rowA;
        f32x16 accS;
        #pragma unroll
        for (int r = 0; r < 16; ++r) accS[r] = 0.f;
        #pragma unroll
        for (int ks = 0; ks < 8; ++ks) {
            int ch = 2 * ks + hi;
            bf16x8 a = *(const bf16x8*)&hL[rowA * 128 + ((ch ^ (rowA & 15)) << 3)];
            bf16x8 bb = *(const bf16x8*)&wst[((wave * 8 + ks) * 64 + lane) * 8];
            accS = __builtin_amdgcn_mfma_f32_32x32x16_bf16(a, bb, accS, 0, 0, 0);
        }
        float b2 = bs2[cN];
        #pragma unroll
        for (int r = 0; r < 16; ++r) {
            int j = (r & 3) + 8 * (r >> 2) + 4 * hi;
            if (j < NOBJ)
                fL[j * 256 + (((cN >> 3) ^ (j & 15)) << 3) + (cN & 7)] = (__bf16)ftanh(accS[r] + b2);
        }
    } else {
        float acc[11];
        #pragma unroll
        for (int g = 0; g < 11; ++g) acc[g] = 0.f;
        const unsigned int* hrow = (const unsigned int*)hL;
        for (int k2 = 0; k2 < 64; ++k2) {
            float w0 = Ws2[(2 * k2) * 128 + c];
            float w1 = Ws2[(2 * k2 + 1) * 128 + c];
            #pragma unroll
            for (int g = 0; g < 11; ++g) {
                if (g < NI) {
                    int i = i0 + g;
                    unsigned int pr = hrow[i * 64 + (((k2 >> 2) ^ (i & 15)) << 2) + (k2 & 3)];
                    float lo = __uint_as_float(pr << 16);
                    float hh = __uint_as_float(pr & 0xffff0000u);
                    acc[g] = __builtin_fmaf(hh, w1, __builtin_fmaf(lo, w0, acc[g]));
                }
            }
        }
        float b2 = bs2[c];
        for (int g = 0; g < NI; ++g) {
            int i = i0 + g;
            fL[i * 256 + (((c >> 3) ^ (i & 15)) << 3) + (c & 7)] = (__bf16)ftanh(acc[g] + b2);
        }
    }
    for (int idx = tid; idx < NOBJ * 64; idx += 256) {
        int i = idx >> 6, e = idx & 63;
        fL[i * 256 + ((((16 + (e >> 3)) ^ (i & 15))) << 3) + (e & 7)] = (__bf16)fe3[catl[i] * 64 + e];
    }
    __syncthreads();

    // ---- step 3: u,v (PRE-SCALED by 2log2e) via 32x32 MFMA, interleaved dual acc ----
    if constexpr (WS >= 1) {
        const int cN = wave * 32 + rowA;
        const int jcA = rowA < NOBJ ? rowA : NOBJ - 1;
        f32x16 accU, accV;
        #pragma unroll
        for (int r = 0; r < 16; ++r) { accU[r] = 0.f; accV[r] = 0.f; }
        #pragma unroll
        for (int ks = 0; ks < 12; ++ks) {
            int ch = 2 * ks + hi;
            bf16x8 a = *(const bf16x8*)&fL[jcA * 256 + ((ch ^ (jcA & 15)) << 3)];
            int fi = (wave * 12 + ks) * 64 + lane;
            bf16x8 bu = *(const bf16x8*)&wdt[fi * 8];
            bf16x8 bv = *(const bf16x8*)&wbt[fi * 8];
            accU = __builtin_amdgcn_mfma_f32_32x32x16_bf16(a, bu, accU, 0, 0, 0);
            accV = __builtin_amdgcn_mfma_f32_32x32x16_bf16(a, bv, accV, 0, 0, 0);
        }
        float b1s = bm1[cN] * PRESCALE;
        #pragma unroll
        for (int r = 0; r < 16; ++r) {
            int j = (r & 3) + 8 * (r >> 2) + 4 * hi;
            if (j < NOBJ) {
                uL[uvswz(j, cN)] = __builtin_fmaf(accU[r], PRESCALE, b1s);
                vL[uvswz(j, cN)] = accV[r] * PRESCALE;
            }
        }
    } else {
        float ua[11], va[11];
        #pragma unroll
        for (int g = 0; g < 11; ++g) { ua[g] = 0.f; va[g] = 0.f; }
        const unsigned int* frow = (const unsigned int*)fL;   // row stride 128 dwords
        for (int k2 = 0; k2 < 96; ++k2) {
            int k = 2 * k2;
            float wt0 = Wm1[k * 128 + c],         wt1 = Wm1[(k + 1) * 128 + c];
            float wb0 = Wm1[(192 + k) * 128 + c], wb1 = Wm1[(193 + k) * 128 + c];
            float wd0 = wt0 - wb0, wd1 = wt1 - wb1;
            #pragma unroll
            for (int g = 0; g < 11; ++g) {
                if (g < NI) {
                    int i = i0 + g;
                    unsigned int pr = frow[i * 128 + (((k2 >> 2) ^ (i & 15)) << 2) + (k2 & 3)];
                    float lo = __uint_as_float(pr << 16);
                    float hh = __uint_as_float(pr & 0xffff0000u);
                    ua[g] = __builtin_fmaf(hh, wd1, __builtin_fmaf(lo, wd0, ua[g]));
                    va[g] = __builtin_fmaf(hh, wb1, __builtin_fmaf(lo, wb0, va[g]));
                }
            }
        }
        float b1 = bm1[c];
        for (int g = 0; g < NI; ++g) {
            uL[uvswz(i0 + g, c)] = (ua[g] + b1) * PRESCALE;
            vL[uvswz(i0 + g, c)] = va[g] * PRESCALE;
        }
    }
    __syncthreads();

    // ---- phase 2: 16x16x32 MFMA; v-rows hoisted to regs; A built once per i ----
    const int l15 = lane & 15;
    const int l4  = (lane >> 4) & 3;
    const int j1c = (16 + l15) < NOBJ ? (16 + l15) : NOBJ - 1;
    float bm2v[8];
    #pragma unroll
    for (int nt = 0; nt < 8; ++nt) bm2v[nt] = bm2[nt * 16 + l15];

    // hoist i-invariant v reads: rows l15 (tile0) and j1c (tile1), k = kf*8+l4*2 chunks
    f32x4 vr0[4], vr1[4], vr2[4], vr3[4];
    #pragma unroll
    for (int kf = 0; kf < 4; ++kf) {
        int c0 = kf * 8 + l4 * 2;
        vr0[kf] = *(const f32x4*)&vL[l15 * 128 + (((c0)     ^ l15) << 2)];
        vr1[kf] = *(const f32x4*)&vL[l15 * 128 + (((c0 + 1) ^ l15) << 2)];
        vr2[kf] = *(const f32x4*)&vL[j1c * 128 + (((c0)     ^ (j1c & 15)) << 2)];
        vr3[kf] = *(const f32x4*)&vL[j1c * 128 + (((c0 + 1) ^ (j1c & 15)) << 2)];
    }

    for (int i = wave; i < NOBJ; i += 4) {
        bf16x8 A0[4], A1[4];
        #pragma unroll
        for (int kf = 0; kf < 4; ++kf) {
            int c0 = kf * 8 + l4 * 2;
            f32x4 u0 = *(const f32x4*)&uL[i * 128 + (((c0)     ^ (i & 15)) << 2)];
            f32x4 u1 = *(const f32x4*)&uL[i * 128 + (((c0 + 1) ^ (i & 15)) << 2)];
            bf16x8 a0f, a1f;
            #pragma unroll
            for (int e = 0; e < 4; ++e) {
                a0f[e]     = (__bf16)ftanh_pre(u0[e] + vr0[kf][e]);
                a0f[4 + e] = (__bf16)ftanh_pre(u1[e] + vr1[kf][e]);
                a1f[e]     = (__bf16)ftanh_pre(u0[e] + vr2[kf][e]);
                a1f[4 + e] = (__bf16)ftanh_pre(u1[e] + vr3[kf][e]);
            }
            A0[kf] = a0f; A1[kf] = a1f;
        }
        #pragma unroll
        for (int nt = 0; nt < 8; ++nt) {
            f32x4 c0a, c1a;
            #pragma unroll
            for (int r = 0; r < 4; ++r) { c0a[r] = 0.f; c1a[r] = 0.f; }
            #pragma unroll
            for (int kf = 0; kf < 4; ++kf) {
                bf16x8 bb;
                if constexpr (WS >= 1) {
                    bb = *(const bf16x8*)&w2s[((nt * 4 + kf) * 64 + lane) * 8];
                } else {
                    int k0 = kf * 32 + l4 * 8;
                    #pragma unroll
                    for (int e = 0; e < 8; ++e)
                        bb[e] = (__bf16)Wm2[(k0 + e) * 128 + nt * 16 + l15];
                }
                c0a = __builtin_amdgcn_mfma_f32_16x16x32_bf16(A0[kf], bb, c0a, 0, 0, 0);
                c1a = __builtin_amdgcn_mfma_f32_16x16x32_bf16(A1[kf], bb, c1a, 0, 0, 0);
            }
            // D layout 16x16: col = lane&15, row = (lane>>4)*4 + r
            float m = -INFINITY;
            #pragma unroll
            for (int r = 0; r < 4; ++r) {
                int j = l4 * 4 + r;
                if (j != i) m = fmaxf(m, c0a[r]);
            }
            #pragma unroll
            for (int r = 0; r < 4; ++r) {
                int j = 16 + l4 * 4 + r;
                if (j < NOBJ && j != i) m = fmaxf(m, c1a[r]);
            }
            m = fmaxf(m, __shfl_xor(m, 16));
            m = fmaxf(m, __shfl_xor(m, 32));
            if (lane < 16) xL[bswz(i, nt * 16 + l15)] = (__bf16)ftanh(m + bm2v[nt]);
        }
    }
    __syncthreads();

    // ---- phase 3: a1 = tanh(x @ Wa1 + ba1) -> f32 a1L (overlays uL) ----
    if constexpr (WS == 2) {
        const int cN = wave * 32 + rowA;
        f32x16 accP;
        #pragma unroll
        for (int r = 0; r < 16; ++r) accP[r] = 0.f;
        #pragma unroll
        for (int ks = 0; ks < 8; ++ks) {
            int ch = 2 * ks + hi;
            bf16x8 a = *(const bf16x8*)&xL[rowA * 128 + ((ch ^ (rowA & 15)) << 3)];
            bf16x8 bb = *(const bf16x8*)&wat[((wave * 8 + ks) * 64 + lane) * 8];
            accP = __builtin_amdgcn_mfma_f32_32x32x16_bf16(a, bb, accP, 0, 0, 0);
        }
        float b1 = ba1[cN];
        __syncthreads();   // uL reads (phase 2) fully done before a1L overlay write
        #pragma unroll
        for (int r = 0; r < 16; ++r) {
            int j = (r & 3) + 8 * (r >> 2) + 4 * hi;
            if (j < NOBJ) a1L[j * 128 + cN] = ftanh(accP[r] + b1);
        }
    } else {
        float acc[11];
        #pragma unroll
        for (int g = 0; g < 11; ++g) acc[g] = 0.f;
        const unsigned int* xrow = (const unsigned int*)xL;
        for (int k2 = 0; k2 < 64; ++k2) {
            float w0 = Wa1[(2 * k2) * 128 + c];
            float w1 = Wa1[(2 * k2 + 1) * 128 + c];
            #pragma unroll
            for (int g = 0; g < 11; ++g) {
                if (g < NI) {
                    int i = i0 + g;
                    unsigned int pr = xrow[i * 64 + (((k2 >> 2) ^ (i & 15)) << 2) + (k2 & 3)];
                    float lo = __uint_as_float(pr << 16);
                    float hh = __uint_as_float(pr & 0xffff0000u);
                    acc[g] = __builtin_fmaf(hh, w1, __builtin_fmaf(lo, w0, acc[g]));
                }
            }
        }
        float b1 = ba1[c];
        __syncthreads();
        for (int g = 0; g < NI; ++g)
            a1L[(i0 + g) * 128 + c] = ftanh(acc[g] + b1);
    }
    __syncthreads();

    // ---- head: 4 ILP accumulators, f32x4 reads, i-rotated to spread banks ----
    if (tid < NOBJ * 4) {
        int i = tid >> 2, o = tid & 3;
        float ac0 = ba2[o], ac1 = 0.f, ac2 = 0.f, ac3 = 0.f;
        for (int k4 = 0; k4 < 32; ++k4) {
            int kr = (k4 + i) & 31;
            f32x4 av = *(const f32x4*)&a1L[i * 128 + kr * 4];
            ac0 = __builtin_fmaf(av[0], Wa2[(kr * 4 + 0) * 4 + o], ac0);
            ac1 = __builtin_fmaf(av[1], Wa2[(kr * 4 + 1) * 4 + o], ac1);
            ac2 = __builtin_fmaf(av[2], Wa2[(kr * 4 + 2) * 4 + o], ac2);
            ac3 = __builtin_fmaf(av[3], Wa2[(kr * 4 + 3) * 4 + o], ac3);
        }
        float acc = (ac0 + ac1) + (ac2 + ac3);
        if (o < 2) {
            out[b * 42 + i * 2 + o] = 0.3f * ftanh(acc);
        } else {
            float t   = ftanh(acc);
            float lsv = -5.0f + 3.5f * (t + 1.0f);
            out[43008 + b * 42 + i * 2 + (o - 2)] = __expf(lsv);
        }
    }
}

extern "C" void kernel_launch(void* const* d_in, const int* in_sizes, int n_in,
                              void* d_out, int out_size, void* d_ws, size_t ws_size,
                              hipStream_t stream) {
    (void)in_sizes; (void)n_in; (void)out_size;
    const float* state = (const float*)d_in[0];
    const float* ts    = (const float*)d_in[1];
    const float* emb   = (const float*)d_in[2];
    const float* We    = (const float*)d_in[3];
    const float* be    = (const float*)d_in[4];
    const float* Ws1   = (const float*)d_in[5];
    const float* bs1   = (const float*)d_in[6];
    const float* Ws2   = (const float*)d_in[7];
    const float* bs2   = (const float*)d_in[8];
    const float* Wm1   = (const float*)d_in[9];
    const float* bm1   = (const float*)d_in[10];
    const float* Wm2   = (const float*)d_in[11];
    const float* bm2   = (const float*)d_in[12];
    const float* Wa1   = (const float*)d_in[13];
    const float* ba1   = (const float*)d_in[14];
    const float* Wa2   = (const float*)d_in[15];
    const float* ba2   = (const float*)d_in[16];
    float* outp = (float*)d_out;

    float*  fe3 = (float*)d_ws;
    __bf16* w2s = (__bf16*)((char*)d_ws + 1024);
    __bf16* wdt = (__bf16*)((char*)d_ws + 33792);
    __bf16* wbt = (__bf16*)((char*)d_ws + 82944);
    __bf16* wst = (__bf16*)((char*)d_ws + 132096);
    __bf16* wat = (__bf16*)((char*)d_ws + 164864);
    const size_t need1 = 132096, need2 = 197632;
    const int level = (ws_size >= need2) ? 2 : ((ws_size >= need1) ? 1 : 0);

    setup_kernel<<<dim3(49), dim3(256), 0, stream>>>(emb, We, be, Wm2, Wm1, Ws2, Wa1,
                                                     fe3, w2s, wdt, wbt, wst, wat, level);
    if (level == 2)
        actor_kernel<2><<<dim3(1024), dim3(256), 0, stream>>>(
            state, ts, Ws1, bs1, Ws2, bs2, Wm1, bm1, Wm2, bm2,
            Wa1, ba1, Wa2, ba2, fe3, w2s, wdt, wbt, wst, wat, outp);
    else if (level == 1)
        actor_kernel<1><<<dim3(1024), dim3(256), 0, stream>>>(
            state, ts, Ws1, bs1, Ws2, bs2, Wm1, bm1, Wm2, bm2,
            Wa1, ba1, Wa2, ba2, fe3, w2s, wdt, wbt, wst, wat, outp);
    else
        actor_kernel<0><<<dim3(1024), dim3(256), 0, stream>>>(
            state, ts, Ws1, bs1, Ws2, bs2, Wm1, bm1, Wm2, bm2,
            Wa1, ba1, Wa2, ba2, fe3, w2s, wdt, wbt, wst, wat, outp);
}

// Round 13
// 77.938 us; speedup vs baseline: 1.2453x; 1.1691x over previous
//
#include <hip/hip_runtime.h>
#include <hip/hip_bf16.h>

#define NOBJ 21

typedef __bf16 bf16x8 __attribute__((ext_vector_type(8)));
typedef float f32x16 __attribute__((ext_vector_type(16)));
typedef float f32x4  __attribute__((ext_vector_type(4)));

#define PRESCALE 2.8853900817779268f   // 2*log2(e)

__device__ __forceinline__ float ftanh(float x) {
    // tanh(x) = 1 - 2/(exp2(x*2*log2e)+1)
    float e = __builtin_amdgcn_exp2f(x * PRESCALE);
    float r = __builtin_amdgcn_rcpf(e + 1.0f);
    return __builtin_fmaf(-2.0f, r, 1.0f);
}
__device__ __forceinline__ float ftanh_pre(float xp) {
    // xp already scaled by PRESCALE
    float e = __builtin_amdgcn_exp2f(xp);
    float r = __builtin_amdgcn_rcpf(e + 1.0f);
    return __builtin_fmaf(-2.0f, r, 1.0f);
}

// ---------------- workspace layout ----------------
// fe3 @0 (1024) | w2s @1024 (32768) | wdt @33792 (49152) | wbt @82944 (49152)
// wst @132096 (32768) | wat @164864 (32768)   total 197632
// w2s: Wm2 in 16x16x32 B-frag layout: fi=(nt*4+kf)*64+lane,
//      elem e = Wm2[kf*32+(lane>>4)*8+e][nt*16+(lane&15)]
// wdt/wbt/wst/wat: 32x32x16 B-frag layout (verified in-kernel):
//      col n = ct*32+(lane&31), k = ks*16+(lane>>5)*8+e
__global__ void setup_kernel(const float* __restrict__ emb, const float* __restrict__ We,
                             const float* __restrict__ be, const float* __restrict__ Wm2,
                             const float* __restrict__ Wm1, const float* __restrict__ Ws2,
                             const float* __restrict__ Wa1,
                             float* __restrict__ fe3, __bf16* __restrict__ w2s,
                             __bf16* __restrict__ wdt, __bf16* __restrict__ wbt,
                             __bf16* __restrict__ wst, __bf16* __restrict__ wat,
                             int level) {
    int t = threadIdx.x;
    if (blockIdx.x == 48) {
        if (t < 192) {
            int cc = t >> 6, e = t & 63;
            float acc = be[e];
            for (int k = 0; k < 64; ++k)
                acc += ftanh(emb[cc * 64 + k]) * We[k * 64 + e];
            fe3[t] = ftanh(acc);
        }
        return;
    }
    int fid = blockIdx.x * 256 + t;   // 0..12287
    if (fid < 2048) {                 // w2s: 16x16 frags (K=128 -> kf 0..3, nt 0..7)
        if (level < 1) return;
        int nt = fid >> 8, kf = (fid >> 6) & 3, ln = fid & 63;
        int n  = nt * 16 + (ln & 15);
        int k0 = kf * 32 + ((ln >> 4) & 3) * 8;
        bf16x8 v;
        #pragma unroll
        for (int e = 0; e < 8; ++e) v[e] = (__bf16)Wm2[(k0 + e) * 128 + n];
        *reinterpret_cast<bf16x8*>(&w2s[fid * 8]) = v;
    } else if (fid < 5120) {          // wdt (K=192)
        if (level < 1) return;
        int q = fid - 2048;
        int ct = q / 768, r = q % 768, ks = r >> 6, ln = r & 63;
        int n = ct * 32 + (ln & 31), k0 = ks * 16 + (ln >> 5) * 8;
        bf16x8 v;
        #pragma unroll
        for (int e = 0; e < 8; ++e)
            v[e] = (__bf16)(Wm1[(k0 + e) * 128 + n] - Wm1[(192 + k0 + e) * 128 + n]);
        *reinterpret_cast<bf16x8*>(&wdt[q * 8]) = v;
    } else if (fid < 8192) {          // wbt (K=192)
        if (level < 1) return;
        int q = fid - 5120;
        int ct = q / 768, r = q % 768, ks = r >> 6, ln = r & 63;
        int n = ct * 32 + (ln & 31), k0 = ks * 16 + (ln >> 5) * 8;
        bf16x8 v;
        #pragma unroll
        for (int e = 0; e < 8; ++e) v[e] = (__bf16)Wm1[(192 + k0 + e) * 128 + n];
        *reinterpret_cast<bf16x8*>(&wbt[q * 8]) = v;
    } else if (fid < 10240) {         // wst (K=128)
        if (level < 2) return;
        int q = fid - 8192;
        int ct = q >> 9, ks = (q >> 6) & 7, ln = q & 63;
        int n = ct * 32 + (ln & 31), k0 = ks * 16 + (ln >> 5) * 8;
        bf16x8 v;
        #pragma unroll
        for (int e = 0; e < 8; ++e) v[e] = (__bf16)Ws2[(k0 + e) * 128 + n];
        *reinterpret_cast<bf16x8*>(&wst[q * 8]) = v;
    } else {                          // wat (K=128)
        if (level < 2) return;
        int q = fid - 10240;
        int ct = q >> 9, ks = (q >> 6) & 7, ln = q & 63;
        int n = ct * 32 + (ln & 31), k0 = ks * 16 + (ln >> 5) * 8;
        bf16x8 v;
        #pragma unroll
        for (int e = 0; e < 8; ++e) v[e] = (__bf16)Wa1[(k0 + e) * 128 + n];
        *reinterpret_cast<bf16x8*>(&wat[q * 8]) = v;
    }
}

// f32 LDS 16B-chunk XOR swizzle (row-major [*][128] f32)
__device__ __forceinline__ int uvswz(int row, int k) {
    return row * 128 + (((k >> 2) ^ (row & 15)) << 2) + (k & 3);
}
// bf16 LDS 16B-chunk XOR swizzle (row-major [*][128] bf16)
__device__ __forceinline__ int bswz(int row, int k) {
    return row * 128 + (((k >> 3) ^ (row & 15)) << 3) + (k & 7);
}

// LDS layout (40448 B):
//   @0     hL bf16 swz [32][128] (steps1-2) | overlay: uL f32 swz [21][128] (step3+),
//          then a1L f32 [21][128] (phase3+)
//   @10752 vL f32 swz [21][128] | overlay: spl f32[84]+cat int[21] (steps 0-1)
//   @21504 fL bf16 swz [21][256] 10752
//   @32256 xL bf16 swz [32][128] 8192
// NOTE: uL/vL hold PRE-SCALED (×2log2e) values; consumed only by phase-2 tanh.
#define SMEM_SZ 40448

template<int WS>
__global__ __launch_bounds__(256, 2)
void actor_kernel(const float* __restrict__ state, const float* __restrict__ ts,
                  const float* __restrict__ Ws1, const float* __restrict__ bs1,
                  const float* __restrict__ Ws2, const float* __restrict__ bs2,
                  const float* __restrict__ Wm1, const float* __restrict__ bm1,
                  const float* __restrict__ Wm2, const float* __restrict__ bm2,
                  const float* __restrict__ Wa1, const float* __restrict__ ba1,
                  const float* __restrict__ Wa2, const float* __restrict__ ba2,
                  const float* __restrict__ fe3, const __bf16* __restrict__ w2s,
                  const __bf16* __restrict__ wdt, const __bf16* __restrict__ wbt,
                  const __bf16* __restrict__ wst, const __bf16* __restrict__ wat,
                  float* __restrict__ out) {
    __shared__ __align__(16) unsigned char smem[SMEM_SZ];
    __bf16* hL  = (__bf16*)(smem);
    float*  uL  = (float*)(smem);
    float*  a1L = (float*)(smem);
    float*  vL  = (float*)(smem + 10752);
    float*  spl = (float*)(smem + 10752);
    int*    catl= (int*)(smem + 10752 + 336);
    __bf16* fL  = (__bf16*)(smem + 21504);
    __bf16* xL  = (__bf16*)(smem + 32256);

    const int b   = blockIdx.x;
    const int tid = threadIdx.x;
    const int c   = tid & 127;
    const int half= tid >> 7;
    const int i0  = half ? 11 : 0;
    const int NI  = half ? (NOBJ - 11) : 11;
    const int lane = tid & 63;
    const int wave = tid >> 6;
    const int rowA = lane & 31;
    const int hi   = lane >> 5;

    // ---- step 0 ----
    if (tid < NOBJ * 4) {
        int i = tid >> 2, m = tid & 3;
        float v;
        if (m < 2) v = state[b * 63 + i * 3 + m];
        else       v = ftanh(ts[(b * NOBJ + i) * 2 + (m - 2)]);
        spl[tid] = v;
    }
    if (tid >= 128 && tid < 128 + NOBJ) {
        int i = tid - 128;
        catl[i] = (int)state[b * 63 + i * 3 + 2];
    }
    __syncthreads();

    // ---- step 1: h = tanh(sp @ Ws1 + bs1) -> swizzled bf16 hL ----
    {
        float b1 = bs1[c];
        float w0 = Ws1[0 * 128 + c], w1 = Ws1[1 * 128 + c];
        float w2 = Ws1[2 * 128 + c], w3 = Ws1[3 * 128 + c];
        for (int g = 0; g < NI; ++g) {
            int i = i0 + g;
            float acc = b1 + spl[i*4+0]*w0 + spl[i*4+1]*w1 + spl[i*4+2]*w2 + spl[i*4+3]*w3;
            hL[bswz(i, c)] = (__bf16)ftanh(acc);
        }
    }
    __syncthreads();

    // ---- step 2: f[:, :128] = tanh(h @ Ws2 + bs2) -> swizzled bf16 fL ----
    if constexpr (WS == 2) {
        const int cN = wave * 32 + rowA;
        f32x16 accS;
        #pragma unroll
        for (int r = 0; r < 16; ++r) accS[r] = 0.f;
        #pragma unroll
        for (int ks = 0; ks < 8; ++ks) {
            int ch = 2 * ks + hi;
            bf16x8 a = *(const bf16x8*)&hL[rowA * 128 + ((ch ^ (rowA & 15)) << 3)];
            bf16x8 bb = *(const bf16x8*)&wst[((wave * 8 + ks) * 64 + lane) * 8];
            accS = __builtin_amdgcn_mfma_f32_32x32x16_bf16(a, bb, accS, 0, 0, 0);
        }
        float b2 = bs2[cN];
        #pragma unroll
        for (int r = 0; r < 16; ++r) {
            int j = (r & 3) + 8 * (r >> 2) + 4 * hi;
            if (j < NOBJ)
                fL[j * 256 + (((cN >> 3) ^ (j & 15)) << 3) + (cN & 7)] = (__bf16)ftanh(accS[r] + b2);
        }
    } else {
        float acc[11];
        #pragma unroll
        for (int g = 0; g < 11; ++g) acc[g] = 0.f;
        const unsigned int* hrow = (const unsigned int*)hL;
        for (int k2 = 0; k2 < 64; ++k2) {
            float w0 = Ws2[(2 * k2) * 128 + c];
            float w1 = Ws2[(2 * k2 + 1) * 128 + c];
            #pragma unroll
            for (int g = 0; g < 11; ++g) {
                if (g < NI) {
                    int i = i0 + g;
                    unsigned int pr = hrow[i * 64 + (((k2 >> 2) ^ (i & 15)) << 2) + (k2 & 3)];
                    float lo = __uint_as_float(pr << 16);
                    float hh = __uint_as_float(pr & 0xffff0000u);
                    acc[g] = __builtin_fmaf(hh, w1, __builtin_fmaf(lo, w0, acc[g]));
                }
            }
        }
        float b2 = bs2[c];
        for (int g = 0; g < NI; ++g) {
            int i = i0 + g;
            fL[i * 256 + (((c >> 3) ^ (i & 15)) << 3) + (c & 7)] = (__bf16)ftanh(acc[g] + b2);
        }
    }
    for (int idx = tid; idx < NOBJ * 64; idx += 256) {
        int i = idx >> 6, e = idx & 63;
        fL[i * 256 + ((((16 + (e >> 3)) ^ (i & 15))) << 3) + (e & 7)] = (__bf16)fe3[catl[i] * 64 + e];
    }
    __syncthreads();

    // ---- step 3: u,v (PRE-SCALED by 2log2e) via 32x32 MFMA, interleaved dual acc ----
    if constexpr (WS >= 1) {
        const int cN = wave * 32 + rowA;
        const int jcA = rowA < NOBJ ? rowA : NOBJ - 1;
        f32x16 accU, accV;
        #pragma unroll
        for (int r = 0; r < 16; ++r) { accU[r] = 0.f; accV[r] = 0.f; }
        #pragma unroll
        for (int ks = 0; ks < 12; ++ks) {
            int ch = 2 * ks + hi;
            bf16x8 a = *(const bf16x8*)&fL[jcA * 256 + ((ch ^ (jcA & 15)) << 3)];
            int fi = (wave * 12 + ks) * 64 + lane;
            bf16x8 bu = *(const bf16x8*)&wdt[fi * 8];
            bf16x8 bv = *(const bf16x8*)&wbt[fi * 8];
            accU = __builtin_amdgcn_mfma_f32_32x32x16_bf16(a, bu, accU, 0, 0, 0);
            accV = __builtin_amdgcn_mfma_f32_32x32x16_bf16(a, bv, accV, 0, 0, 0);
        }
        float b1s = bm1[cN] * PRESCALE;
        #pragma unroll
        for (int r = 0; r < 16; ++r) {
            int j = (r & 3) + 8 * (r >> 2) + 4 * hi;
            if (j < NOBJ) {
                uL[uvswz(j, cN)] = __builtin_fmaf(accU[r], PRESCALE, b1s);
                vL[uvswz(j, cN)] = accV[r] * PRESCALE;
            }
        }
    } else {
        float ua[11], va[11];
        #pragma unroll
        for (int g = 0; g < 11; ++g) { ua[g] = 0.f; va[g] = 0.f; }
        const unsigned int* frow = (const unsigned int*)fL;   // row stride 128 dwords
        for (int k2 = 0; k2 < 96; ++k2) {
            int k = 2 * k2;
            float wt0 = Wm1[k * 128 + c],         wt1 = Wm1[(k + 1) * 128 + c];
            float wb0 = Wm1[(192 + k) * 128 + c], wb1 = Wm1[(193 + k) * 128 + c];
            float wd0 = wt0 - wb0, wd1 = wt1 - wb1;
            #pragma unroll
            for (int g = 0; g < 11; ++g) {
                if (g < NI) {
                    int i = i0 + g;
                    unsigned int pr = frow[i * 128 + (((k2 >> 2) ^ (i & 15)) << 2) + (k2 & 3)];
                    float lo = __uint_as_float(pr << 16);
                    float hh = __uint_as_float(pr & 0xffff0000u);
                    ua[g] = __builtin_fmaf(hh, wd1, __builtin_fmaf(lo, wd0, ua[g]));
                    va[g] = __builtin_fmaf(hh, wb1, __builtin_fmaf(lo, wb0, va[g]));
                }
            }
        }
        float b1 = bm1[c];
        for (int g = 0; g < NI; ++g) {
            uL[uvswz(i0 + g, c)] = (ua[g] + b1) * PRESCALE;
            vL[uvswz(i0 + g, c)] = va[g] * PRESCALE;
        }
    }
    __syncthreads();

    // ---- phase 2: 16x16x32 MFMA, A built once per i (v read in-loop, no hoist) ----
    const int l15 = lane & 15;
    const int l4  = (lane >> 4) & 3;
    const int j1c = (16 + l15) < NOBJ ? (16 + l15) : NOBJ - 1;
    float bm2v[8];
    #pragma unroll
    for (int nt = 0; nt < 8; ++nt) bm2v[nt] = bm2[nt * 16 + l15];

    for (int i = wave; i < NOBJ; i += 4) {
        bf16x8 A0[4], A1[4];
        #pragma unroll
        for (int kf = 0; kf < 4; ++kf) {
            int c0 = kf * 8 + l4 * 2;
            f32x4 u0  = *(const f32x4*)&uL[i * 128 + (((c0)     ^ (i & 15)) << 2)];
            f32x4 u1  = *(const f32x4*)&uL[i * 128 + (((c0 + 1) ^ (i & 15)) << 2)];
            f32x4 va0 = *(const f32x4*)&vL[l15 * 128 + (((c0)     ^ l15) << 2)];
            f32x4 va1 = *(const f32x4*)&vL[l15 * 128 + (((c0 + 1) ^ l15) << 2)];
            f32x4 vb0 = *(const f32x4*)&vL[j1c * 128 + (((c0)     ^ (j1c & 15)) << 2)];
            f32x4 vb1 = *(const f32x4*)&vL[j1c * 128 + (((c0 + 1) ^ (j1c & 15)) << 2)];
            bf16x8 a0f, a1f;
            #pragma unroll
            for (int e = 0; e < 4; ++e) {
                a0f[e]     = (__bf16)ftanh_pre(u0[e] + va0[e]);
                a0f[4 + e] = (__bf16)ftanh_pre(u1[e] + va1[e]);
                a1f[e]     = (__bf16)ftanh_pre(u0[e] + vb0[e]);
                a1f[4 + e] = (__bf16)ftanh_pre(u1[e] + vb1[e]);
            }
            A0[kf] = a0f; A1[kf] = a1f;
        }
        #pragma unroll
        for (int nt = 0; nt < 8; ++nt) {
            f32x4 c0a, c1a;
            #pragma unroll
            for (int r = 0; r < 4; ++r) { c0a[r] = 0.f; c1a[r] = 0.f; }
            #pragma unroll
            for (int kf = 0; kf < 4; ++kf) {
                bf16x8 bb;
                if constexpr (WS >= 1) {
                    bb = *(const bf16x8*)&w2s[((nt * 4 + kf) * 64 + lane) * 8];
                } else {
                    int k0 = kf * 32 + l4 * 8;
                    #pragma unroll
                    for (int e = 0; e < 8; ++e)
                        bb[e] = (__bf16)Wm2[(k0 + e) * 128 + nt * 16 + l15];
                }
                c0a = __builtin_amdgcn_mfma_f32_16x16x32_bf16(A0[kf], bb, c0a, 0, 0, 0);
                c1a = __builtin_amdgcn_mfma_f32_16x16x32_bf16(A1[kf], bb, c1a, 0, 0, 0);
            }
            // D layout 16x16: col = lane&15, row = (lane>>4)*4 + r
            float m = -INFINITY;
            #pragma unroll
            for (int r = 0; r < 4; ++r) {
                int j = l4 * 4 + r;
                if (j != i) m = fmaxf(m, c0a[r]);
            }
            #pragma unroll
            for (int r = 0; r < 4; ++r) {
                int j = 16 + l4 * 4 + r;
                if (j < NOBJ && j != i) m = fmaxf(m, c1a[r]);
            }
            m = fmaxf(m, __shfl_xor(m, 16));
            m = fmaxf(m, __shfl_xor(m, 32));
            if (lane < 16) xL[bswz(i, nt * 16 + l15)] = (__bf16)ftanh(m + bm2v[nt]);
        }
    }
    __syncthreads();

    // ---- phase 3: a1 = tanh(x @ Wa1 + ba1) -> f32 a1L (overlays uL) ----
    if constexpr (WS == 2) {
        const int cN = wave * 32 + rowA;
        f32x16 accP;
        #pragma unroll
        for (int r = 0; r < 16; ++r) accP[r] = 0.f;
        #pragma unroll
        for (int ks = 0; ks < 8; ++ks) {
            int ch = 2 * ks + hi;
            bf16x8 a = *(const bf16x8*)&xL[rowA * 128 + ((ch ^ (rowA & 15)) << 3)];
            bf16x8 bb = *(const bf16x8*)&wat[((wave * 8 + ks) * 64 + lane) * 8];
            accP = __builtin_amdgcn_mfma_f32_32x32x16_bf16(a, bb, accP, 0, 0, 0);
        }
        float b1 = ba1[cN];
        __syncthreads();   // uL reads (phase 2) fully done before a1L overlay write
        #pragma unroll
        for (int r = 0; r < 16; ++r) {
            int j = (r & 3) + 8 * (r >> 2) + 4 * hi;
            if (j < NOBJ) a1L[j * 128 + cN] = ftanh(accP[r] + b1);
        }
    } else {
        float acc[11];
        #pragma unroll
        for (int g = 0; g < 11; ++g) acc[g] = 0.f;
        const unsigned int* xrow = (const unsigned int*)xL;
        for (int k2 = 0; k2 < 64; ++k2) {
            float w0 = Wa1[(2 * k2) * 128 + c];
            float w1 = Wa1[(2 * k2 + 1) * 128 + c];
            #pragma unroll
            for (int g = 0; g < 11; ++g) {
                if (g < NI) {
                    int i = i0 + g;
                    unsigned int pr = xrow[i * 64 + (((k2 >> 2) ^ (i & 15)) << 2) + (k2 & 3)];
                    float lo = __uint_as_float(pr << 16);
                    float hh = __uint_as_float(pr & 0xffff0000u);
                    acc[g] = __builtin_fmaf(hh, w1, __builtin_fmaf(lo, w0, acc[g]));
                }
            }
        }
        float b1 = ba1[c];
        __syncthreads();
        for (int g = 0; g < NI; ++g)
            a1L[(i0 + g) * 128 + c] = ftanh(acc[g] + b1);
    }
    __syncthreads();

    // ---- head: 4 ILP accumulators, f32x4 reads, i-rotated to spread banks ----
    if (tid < NOBJ * 4) {
        int i = tid >> 2, o = tid & 3;
        float ac0 = ba2[o], ac1 = 0.f, ac2 = 0.f, ac3 = 0.f;
        for (int k4 = 0; k4 < 32; ++k4) {
            int kr = (k4 + i) & 31;
            f32x4 av = *(const f32x4*)&a1L[i * 128 + kr * 4];
            ac0 = __builtin_fmaf(av[0], Wa2[(kr * 4 + 0) * 4 + o], ac0);
            ac1 = __builtin_fmaf(av[1], Wa2[(kr * 4 + 1) * 4 + o], ac1);
            ac2 = __builtin_fmaf(av[2], Wa2[(kr * 4 + 2) * 4 + o], ac2);
            ac3 = __builtin_fmaf(av[3], Wa2[(kr * 4 + 3) * 4 + o], ac3);
        }
        float acc = (ac0 + ac1) + (ac2 + ac3);
        if (o < 2) {
            out[b * 42 + i * 2 + o] = 0.3f * ftanh(acc);
        } else {
            float t   = ftanh(acc);
            float lsv = -5.0f + 3.5f * (t + 1.0f);
            out[43008 + b * 42 + i * 2 + (o - 2)] = __expf(lsv);
        }
    }
}

extern "C" void kernel_launch(void* const* d_in, const int* in_sizes, int n_in,
                              void* d_out, int out_size, void* d_ws, size_t ws_size,
                              hipStream_t stream) {
    (void)in_sizes; (void)n_in; (void)out_size;
    const float* state = (const float*)d_in[0];
    const float* ts    = (const float*)d_in[1];
    const float* emb   = (const float*)d_in[2];
    const float* We    = (const float*)d_in[3];
    const float* be    = (const float*)d_in[4];
    const float* Ws1   = (const float*)d_in[5];
    const float* bs1   = (const float*)d_in[6];
    const float* Ws2   = (const float*)d_in[7];
    const float* bs2   = (const float*)d_in[8];
    const float* Wm1   = (const float*)d_in[9];
    const float* bm1   = (const float*)d_in[10];
    const float* Wm2   = (const float*)d_in[11];
    const float* bm2   = (const float*)d_in[12];
    const float* Wa1   = (const float*)d_in[13];
    const float* ba1   = (const float*)d_in[14];
    const float* Wa2   = (const float*)d_in[15];
    const float* ba2   = (const float*)d_in[16];
    float* outp = (float*)d_out;

    float*  fe3 = (float*)d_ws;
    __bf16* w2s = (__bf16*)((char*)d_ws + 1024);
    __bf16* wdt = (__bf16*)((char*)d_ws + 33792);
    __bf16* wbt = (__bf16*)((char*)d_ws + 82944);
    __bf16* wst = (__bf16*)((char*)d_ws + 132096);
    __bf16* wat = (__bf16*)((char*)d_ws + 164864);
    const size_t need1 = 132096, need2 = 197632;
    const int level = (ws_size >= need2) ? 2 : ((ws_size >= need1) ? 1 : 0);

    setup_kernel<<<dim3(49), dim3(256), 0, stream>>>(emb, We, be, Wm2, Wm1, Ws2, Wa1,
                                                     fe3, w2s, wdt, wbt, wst, wat, level);
    if (level == 2)
        actor_kernel<2><<<dim3(1024), dim3(256), 0, stream>>>(
            state, ts, Ws1, bs1, Ws2, bs2, Wm1, bm1, Wm2, bm2,
            Wa1, ba1, Wa2, ba2, fe3, w2s, wdt, wbt, wst, wat, outp);
    else if (level == 1)
        actor_kernel<1><<<dim3(1024), dim3(256), 0, stream>>>(
            state, ts, Ws1, bs1, Ws2, bs2, Wm1, bm1, Wm2, bm2,
            Wa1, ba1, Wa2, ba2, fe3, w2s, wdt, wbt, wst, wat, outp);
    else
        actor_kernel<0><<<dim3(1024), dim3(256), 0, stream>>>(
            state, ts, Ws1, bs1, Ws2, bs2, Wm1, bm1, Wm2, bm2,
            Wa1, ba1, Wa2, ba2, fe3, w2s, wdt, wbt, wst, wat, outp);
}

// Round 14
// 77.076 us; speedup vs baseline: 1.2592x; 1.0112x over previous
//
#include <hip/hip_runtime.h>
#include <hip/hip_bf16.h>

#define NOBJ 21

typedef __bf16 bf16x8 __attribute__((ext_vector_type(8)));
typedef float f32x16 __attribute__((ext_vector_type(16)));
typedef float f32x4  __attribute__((ext_vector_type(4)));

#define PRESCALE 2.8853900817779268f   // 2*log2(e)

__device__ __forceinline__ float ftanh(float x) {
    // tanh(x) = 1 - 2/(exp2(x*2*log2e)+1)
    float e = __builtin_amdgcn_exp2f(x * PRESCALE);
    float r = __builtin_amdgcn_rcpf(e + 1.0f);
    return __builtin_fmaf(-2.0f, r, 1.0f);
}
__device__ __forceinline__ float ftanh_pre(float xp) {
    // xp already scaled by PRESCALE
    float e = __builtin_amdgcn_exp2f(xp);
    float r = __builtin_amdgcn_rcpf(e + 1.0f);
    return __builtin_fmaf(-2.0f, r, 1.0f);
}

// ---------------- workspace layout ----------------
// fe3 @0 (1024) | w2s @1024 (32768) | wdt @33792 (49152) | wbt @82944 (49152)
// wst @132096 (32768) | wat @164864 (32768)   total 197632
// w2s: Wm2 in 16x16x32 B-frag layout: fi=(nt*4+kf)*64+lane,
//      elem e = Wm2[kf*32+(lane>>4)*8+e][nt*16+(lane&15)]
// wdt/wbt/wst/wat: 32x32x16 B-frag layout (verified in-kernel):
//      col n = ct*32+(lane&31), k = ks*16+(lane>>5)*8+e
__global__ void setup_kernel(const float* __restrict__ emb, const float* __restrict__ We,
                             const float* __restrict__ be, const float* __restrict__ Wm2,
                             const float* __restrict__ Wm1, const float* __restrict__ Ws2,
                             const float* __restrict__ Wa1,
                             float* __restrict__ fe3, __bf16* __restrict__ w2s,
                             __bf16* __restrict__ wdt, __bf16* __restrict__ wbt,
                             __bf16* __restrict__ wst, __bf16* __restrict__ wat,
                             int level) {
    int t = threadIdx.x;
    if (blockIdx.x == 48) {
        if (t < 192) {
            int cc = t >> 6, e = t & 63;
            float acc = be[e];
            for (int k = 0; k < 64; ++k)
                acc += ftanh(emb[cc * 64 + k]) * We[k * 64 + e];
            fe3[t] = ftanh(acc);
        }
        return;
    }
    int fid = blockIdx.x * 256 + t;   // 0..12287
    if (fid < 2048) {                 // w2s: 16x16 frags (K=128 -> kf 0..3, nt 0..7)
        if (level < 1) return;
        int nt = fid >> 8, kf = (fid >> 6) & 3, ln = fid & 63;
        int n  = nt * 16 + (ln & 15);
        int k0 = kf * 32 + ((ln >> 4) & 3) * 8;
        bf16x8 v;
        #pragma unroll
        for (int e = 0; e < 8; ++e) v[e] = (__bf16)Wm2[(k0 + e) * 128 + n];
        *reinterpret_cast<bf16x8*>(&w2s[fid * 8]) = v;
    } else if (fid < 5120) {          // wdt (K=192)
        if (level < 1) return;
        int q = fid - 2048;
        int ct = q / 768, r = q % 768, ks = r >> 6, ln = r & 63;
        int n = ct * 32 + (ln & 31), k0 = ks * 16 + (ln >> 5) * 8;
        bf16x8 v;
        #pragma unroll
        for (int e = 0; e < 8; ++e)
            v[e] = (__bf16)(Wm1[(k0 + e) * 128 + n] - Wm1[(192 + k0 + e) * 128 + n]);
        *reinterpret_cast<bf16x8*>(&wdt[q * 8]) = v;
    } else if (fid < 8192) {          // wbt (K=192)
        if (level < 1) return;
        int q = fid - 5120;
        int ct = q / 768, r = q % 768, ks = r >> 6, ln = r & 63;
        int n = ct * 32 + (ln & 31), k0 = ks * 16 + (ln >> 5) * 8;
        bf16x8 v;
        #pragma unroll
        for (int e = 0; e < 8; ++e) v[e] = (__bf16)Wm1[(192 + k0 + e) * 128 + n];
        *reinterpret_cast<bf16x8*>(&wbt[q * 8]) = v;
    } else if (fid < 10240) {         // wst (K=128)
        if (level < 2) return;
        int q = fid - 8192;
        int ct = q >> 9, ks = (q >> 6) & 7, ln = q & 63;
        int n = ct * 32 + (ln & 31), k0 = ks * 16 + (ln >> 5) * 8;
        bf16x8 v;
        #pragma unroll
        for (int e = 0; e < 8; ++e) v[e] = (__bf16)Ws2[(k0 + e) * 128 + n];
        *reinterpret_cast<bf16x8*>(&wst[q * 8]) = v;
    } else {                          // wat (K=128)
        if (level < 2) return;
        int q = fid - 10240;
        int ct = q >> 9, ks = (q >> 6) & 7, ln = q & 63;
        int n = ct * 32 + (ln & 31), k0 = ks * 16 + (ln >> 5) * 8;
        bf16x8 v;
        #pragma unroll
        for (int e = 0; e < 8; ++e) v[e] = (__bf16)Wa1[(k0 + e) * 128 + n];
        *reinterpret_cast<bf16x8*>(&wat[q * 8]) = v;
    }
}

// f32 LDS 16B-chunk XOR swizzle (row-major [*][128] f32)
__device__ __forceinline__ int uvswz(int row, int k) {
    return row * 128 + (((k >> 2) ^ (row & 15)) << 2) + (k & 3);
}
// bf16 LDS 16B-chunk XOR swizzle (row-major [*][128] bf16)
__device__ __forceinline__ int bswz(int row, int k) {
    return row * 128 + (((k >> 3) ^ (row & 15)) << 3) + (k & 7);
}

// LDS layout (40448 B):
//   @0     hL bf16 swz [32][128] (steps1-2) | overlay: uL f32 swz [21][128] (step3+),
//          then a1L f32 [21][128] (phase3+)
//   @10752 vL f32 swz [21][128] | overlay: spl f32[84]+cat int[21] (steps 0-1)
//   @21504 fL bf16 swz [21][256] 10752
//   @32256 xL bf16 swz [32][128] 8192
// NOTE: uL/vL hold PRE-SCALED (×2log2e) values; consumed only by phase-2 tanh.
#define SMEM_SZ 40448

template<int WS>
__global__ __launch_bounds__(256, 2)
void actor_kernel(const float* __restrict__ state, const float* __restrict__ ts,
                  const float* __restrict__ Ws1, const float* __restrict__ bs1,
                  const float* __restrict__ Ws2, const float* __restrict__ bs2,
                  const float* __restrict__ Wm1, const float* __restrict__ bm1,
                  const float* __restrict__ Wm2, const float* __restrict__ bm2,
                  const float* __restrict__ Wa1, const float* __restrict__ ba1,
                  const float* __restrict__ Wa2, const float* __restrict__ ba2,
                  const float* __restrict__ fe3, const __bf16* __restrict__ w2s,
                  const __bf16* __restrict__ wdt, const __bf16* __restrict__ wbt,
                  const __bf16* __restrict__ wst, const __bf16* __restrict__ wat,
                  float* __restrict__ out) {
    __shared__ __align__(16) unsigned char smem[SMEM_SZ];
    __bf16* hL  = (__bf16*)(smem);
    float*  uL  = (float*)(smem);
    float*  a1L = (float*)(smem);
    float*  vL  = (float*)(smem + 10752);
    float*  spl = (float*)(smem + 10752);
    int*    catl= (int*)(smem + 10752 + 336);
    __bf16* fL  = (__bf16*)(smem + 21504);
    __bf16* xL  = (__bf16*)(smem + 32256);

    const int b   = blockIdx.x;
    const int tid = threadIdx.x;
    const int c   = tid & 127;
    const int half= tid >> 7;
    const int i0  = half ? 11 : 0;
    const int NI  = half ? (NOBJ - 11) : 11;
    const int lane = tid & 63;
    const int wave = tid >> 6;
    const int rowA = lane & 31;
    const int hi   = lane >> 5;

    // ---- step 0 ----
    if (tid < NOBJ * 4) {
        int i = tid >> 2, m = tid & 3;
        float v;
        if (m < 2) v = state[b * 63 + i * 3 + m];
        else       v = ftanh(ts[(b * NOBJ + i) * 2 + (m - 2)]);
        spl[tid] = v;
    }
    if (tid >= 128 && tid < 128 + NOBJ) {
        int i = tid - 128;
        catl[i] = (int)state[b * 63 + i * 3 + 2];
    }
    __syncthreads();

    // ---- step 1: h = tanh(sp @ Ws1 + bs1) -> swizzled bf16 hL ----
    {
        float b1 = bs1[c];
        float w0 = Ws1[0 * 128 + c], w1 = Ws1[1 * 128 + c];
        float w2 = Ws1[2 * 128 + c], w3 = Ws1[3 * 128 + c];
        for (int g = 0; g < NI; ++g) {
            int i = i0 + g;
            float acc = b1 + spl[i*4+0]*w0 + spl[i*4+1]*w1 + spl[i*4+2]*w2 + spl[i*4+3]*w3;
            hL[bswz(i, c)] = (__bf16)ftanh(acc);
        }
    }
    __syncthreads();

    // ---- step 2: f[:, :128] = tanh(h @ Ws2 + bs2) -> swizzled bf16 fL ----
    if constexpr (WS == 2) {
        const int cN = wave * 32 + rowA;
        f32x16 accS;
        #pragma unroll
        for (int r = 0; r < 16; ++r) accS[r] = 0.f;
        #pragma unroll
        for (int ks = 0; ks < 8; ++ks) {
            int ch = 2 * ks + hi;
            bf16x8 a = *(const bf16x8*)&hL[rowA * 128 + ((ch ^ (rowA & 15)) << 3)];
            bf16x8 bb = *(const bf16x8*)&wst[((wave * 8 + ks) * 64 + lane) * 8];
            accS = __builtin_amdgcn_mfma_f32_32x32x16_bf16(a, bb, accS, 0, 0, 0);
        }
        float b2 = bs2[cN];
        #pragma unroll
        for (int r = 0; r < 16; ++r) {
            int j = (r & 3) + 8 * (r >> 2) + 4 * hi;
            if (j < NOBJ)
                fL[j * 256 + (((cN >> 3) ^ (j & 15)) << 3) + (cN & 7)] = (__bf16)ftanh(accS[r] + b2);
        }
    } else {
        float acc[11];
        #pragma unroll
        for (int g = 0; g < 11; ++g) acc[g] = 0.f;
        const unsigned int* hrow = (const unsigned int*)hL;
        for (int k2 = 0; k2 < 64; ++k2) {
            float w0 = Ws2[(2 * k2) * 128 + c];
            float w1 = Ws2[(2 * k2 + 1) * 128 + c];
            #pragma unroll
            for (int g = 0; g < 11; ++g) {
                if (g < NI) {
                    int i = i0 + g;
                    unsigned int pr = hrow[i * 64 + (((k2 >> 2) ^ (i & 15)) << 2) + (k2 & 3)];
                    float lo = __uint_as_float(pr << 16);
                    float hh = __uint_as_float(pr & 0xffff0000u);
                    acc[g] = __builtin_fmaf(hh, w1, __builtin_fmaf(lo, w0, acc[g]));
                }
            }
        }
        float b2 = bs2[c];
        for (int g = 0; g < NI; ++g) {
            int i = i0 + g;
            fL[i * 256 + (((c >> 3) ^ (i & 15)) << 3) + (c & 7)] = (__bf16)ftanh(acc[g] + b2);
        }
    }
    for (int idx = tid; idx < NOBJ * 64; idx += 256) {
        int i = idx >> 6, e = idx & 63;
        fL[i * 256 + ((((16 + (e >> 3)) ^ (i & 15))) << 3) + (e & 7)] = (__bf16)fe3[catl[i] * 64 + e];
    }
    __syncthreads();

    // ---- step 3: u,v (PRE-SCALED by 2log2e) via 32x32 MFMA, interleaved dual acc ----
    if constexpr (WS >= 1) {
        const int cN = wave * 32 + rowA;
        const int jcA = rowA < NOBJ ? rowA : NOBJ - 1;
        f32x16 accU, accV;
        #pragma unroll
        for (int r = 0; r < 16; ++r) { accU[r] = 0.f; accV[r] = 0.f; }
        #pragma unroll
        for (int ks = 0; ks < 12; ++ks) {
            int ch = 2 * ks + hi;
            bf16x8 a = *(const bf16x8*)&fL[jcA * 256 + ((ch ^ (jcA & 15)) << 3)];
            int fi = (wave * 12 + ks) * 64 + lane;
            bf16x8 bu = *(const bf16x8*)&wdt[fi * 8];
            bf16x8 bv = *(const bf16x8*)&wbt[fi * 8];
            accU = __builtin_amdgcn_mfma_f32_32x32x16_bf16(a, bu, accU, 0, 0, 0);
            accV = __builtin_amdgcn_mfma_f32_32x32x16_bf16(a, bv, accV, 0, 0, 0);
        }
        float b1s = bm1[cN] * PRESCALE;
        #pragma unroll
        for (int r = 0; r < 16; ++r) {
            int j = (r & 3) + 8 * (r >> 2) + 4 * hi;
            if (j < NOBJ) {
                uL[uvswz(j, cN)] = __builtin_fmaf(accU[r], PRESCALE, b1s);
                vL[uvswz(j, cN)] = accV[r] * PRESCALE;
            }
        }
    } else {
        float ua[11], va[11];
        #pragma unroll
        for (int g = 0; g < 11; ++g) { ua[g] = 0.f; va[g] = 0.f; }
        const unsigned int* frow = (const unsigned int*)fL;   // row stride 128 dwords
        for (int k2 = 0; k2 < 96; ++k2) {
            int k = 2 * k2;
            float wt0 = Wm1[k * 128 + c],         wt1 = Wm1[(k + 1) * 128 + c];
            float wb0 = Wm1[(192 + k) * 128 + c], wb1 = Wm1[(193 + k) * 128 + c];
            float wd0 = wt0 - wb0, wd1 = wt1 - wb1;
            #pragma unroll
            for (int g = 0; g < 11; ++g) {
                if (g < NI) {
                    int i = i0 + g;
                    unsigned int pr = frow[i * 128 + (((k2 >> 2) ^ (i & 15)) << 2) + (k2 & 3)];
                    float lo = __uint_as_float(pr << 16);
                    float hh = __uint_as_float(pr & 0xffff0000u);
                    ua[g] = __builtin_fmaf(hh, wd1, __builtin_fmaf(lo, wd0, ua[g]));
                    va[g] = __builtin_fmaf(hh, wb1, __builtin_fmaf(lo, wb0, va[g]));
                }
            }
        }
        float b1 = bm1[c];
        for (int g = 0; g < NI; ++g) {
            uL[uvswz(i0 + g, c)] = (ua[g] + b1) * PRESCALE;
            vL[uvswz(i0 + g, c)] = va[g] * PRESCALE;
        }
    }
    __syncthreads();

    // ---- phase 2: 16x16x32 MFMA, A built once per i; setprio(1) on MFMA cluster ----
    const int l15 = lane & 15;
    const int l4  = (lane >> 4) & 3;
    const int j1c = (16 + l15) < NOBJ ? (16 + l15) : NOBJ - 1;
    float bm2v[8];
    #pragma unroll
    for (int nt = 0; nt < 8; ++nt) bm2v[nt] = bm2[nt * 16 + l15];

    for (int i = wave; i < NOBJ; i += 4) {
        bf16x8 A0[4], A1[4];
        #pragma unroll
        for (int kf = 0; kf < 4; ++kf) {
            int c0 = kf * 8 + l4 * 2;
            f32x4 u0  = *(const f32x4*)&uL[i * 128 + (((c0)     ^ (i & 15)) << 2)];
            f32x4 u1  = *(const f32x4*)&uL[i * 128 + (((c0 + 1) ^ (i & 15)) << 2)];
            f32x4 va0 = *(const f32x4*)&vL[l15 * 128 + (((c0)     ^ l15) << 2)];
            f32x4 va1 = *(const f32x4*)&vL[l15 * 128 + (((c0 + 1) ^ l15) << 2)];
            f32x4 vb0 = *(const f32x4*)&vL[j1c * 128 + (((c0)     ^ (j1c & 15)) << 2)];
            f32x4 vb1 = *(const f32x4*)&vL[j1c * 128 + (((c0 + 1) ^ (j1c & 15)) << 2)];
            bf16x8 a0f, a1f;
            #pragma unroll
            for (int e = 0; e < 4; ++e) {
                a0f[e]     = (__bf16)ftanh_pre(u0[e] + va0[e]);
                a0f[4 + e] = (__bf16)ftanh_pre(u1[e] + va1[e]);
                a1f[e]     = (__bf16)ftanh_pre(u0[e] + vb0[e]);
                a1f[4 + e] = (__bf16)ftanh_pre(u1[e] + vb1[e]);
            }
            A0[kf] = a0f; A1[kf] = a1f;
        }
        __builtin_amdgcn_s_setprio(1);   // favor this wave while its MFMA cluster runs
        #pragma unroll
        for (int nt = 0; nt < 8; ++nt) {
            f32x4 c0a, c1a;
            #pragma unroll
            for (int r = 0; r < 4; ++r) { c0a[r] = 0.f; c1a[r] = 0.f; }
            #pragma unroll
            for (int kf = 0; kf < 4; ++kf) {
                bf16x8 bb;
                if constexpr (WS >= 1) {
                    bb = *(const bf16x8*)&w2s[((nt * 4 + kf) * 64 + lane) * 8];
                } else {
                    int k0 = kf * 32 + l4 * 8;
                    #pragma unroll
                    for (int e = 0; e < 8; ++e)
                        bb[e] = (__bf16)Wm2[(k0 + e) * 128 + nt * 16 + l15];
                }
                c0a = __builtin_amdgcn_mfma_f32_16x16x32_bf16(A0[kf], bb, c0a, 0, 0, 0);
                c1a = __builtin_amdgcn_mfma_f32_16x16x32_bf16(A1[kf], bb, c1a, 0, 0, 0);
            }
            // D layout 16x16: col = lane&15, row = (lane>>4)*4 + r
            float m = -INFINITY;
            #pragma unroll
            for (int r = 0; r < 4; ++r) {
                int j = l4 * 4 + r;
                if (j != i) m = fmaxf(m, c0a[r]);
            }
            #pragma unroll
            for (int r = 0; r < 4; ++r) {
                int j = 16 + l4 * 4 + r;
                if (j < NOBJ && j != i) m = fmaxf(m, c1a[r]);
            }
            m = fmaxf(m, __shfl_xor(m, 16));
            m = fmaxf(m, __shfl_xor(m, 32));
            if (lane < 16) xL[bswz(i, nt * 16 + l15)] = (__bf16)ftanh(m + bm2v[nt]);
        }
        __builtin_amdgcn_s_setprio(0);
    }
    __syncthreads();

    // ---- phase 3: a1 = tanh(x @ Wa1 + ba1) -> f32 a1L (overlays uL) ----
    if constexpr (WS == 2) {
        const int cN = wave * 32 + rowA;
        f32x16 accP;
        #pragma unroll
        for (int r = 0; r < 16; ++r) accP[r] = 0.f;
        #pragma unroll
        for (int ks = 0; ks < 8; ++ks) {
            int ch = 2 * ks + hi;
            bf16x8 a = *(const bf16x8*)&xL[rowA * 128 + ((ch ^ (rowA & 15)) << 3)];
            bf16x8 bb = *(const bf16x8*)&wat[((wave * 8 + ks) * 64 + lane) * 8];
            accP = __builtin_amdgcn_mfma_f32_32x32x16_bf16(a, bb, accP, 0, 0, 0);
        }
        float b1 = ba1[cN];
        __syncthreads();   // uL reads (phase 2) fully done before a1L overlay write
        #pragma unroll
        for (int r = 0; r < 16; ++r) {
            int j = (r & 3) + 8 * (r >> 2) + 4 * hi;
            if (j < NOBJ) a1L[j * 128 + cN] = ftanh(accP[r] + b1);
        }
    } else {
        float acc[11];
        #pragma unroll
        for (int g = 0; g < 11; ++g) acc[g] = 0.f;
        const unsigned int* xrow = (const unsigned int*)xL;
        for (int k2 = 0; k2 < 64; ++k2) {
            float w0 = Wa1[(2 * k2) * 128 + c];
            float w1 = Wa1[(2 * k2 + 1) * 128 + c];
            #pragma unroll
            for (int g = 0; g < 11; ++g) {
                if (g < NI) {
                    int i = i0 + g;
                    unsigned int pr = xrow[i * 64 + (((k2 >> 2) ^ (i & 15)) << 2) + (k2 & 3)];
                    float lo = __uint_as_float(pr << 16);
                    float hh = __uint_as_float(pr & 0xffff0000u);
                    acc[g] = __builtin_fmaf(hh, w1, __builtin_fmaf(lo, w0, acc[g]));
                }
            }
        }
        float b1 = ba1[c];
        __syncthreads();
        for (int g = 0; g < NI; ++g)
            a1L[(i0 + g) * 128 + c] = ftanh(acc[g] + b1);
    }
    __syncthreads();

    // ---- head: 4 ILP accumulators, f32x4 reads, i-rotated to spread banks ----
    if (tid < NOBJ * 4) {
        int i = tid >> 2, o = tid & 3;
        float ac0 = ba2[o], ac1 = 0.f, ac2 = 0.f, ac3 = 0.f;
        for (int k4 = 0; k4 < 32; ++k4) {
            int kr = (k4 + i) & 31;
            f32x4 av = *(const f32x4*)&a1L[i * 128 + kr * 4];
            ac0 = __builtin_fmaf(av[0], Wa2[(kr * 4 + 0) * 4 + o], ac0);
            ac1 = __builtin_fmaf(av[1], Wa2[(kr * 4 + 1) * 4 + o], ac1);
            ac2 = __builtin_fmaf(av[2], Wa2[(kr * 4 + 2) * 4 + o], ac2);
            ac3 = __builtin_fmaf(av[3], Wa2[(kr * 4 + 3) * 4 + o], ac3);
        }
        float acc = (ac0 + ac1) + (ac2 + ac3);
        if (o < 2) {
            out[b * 42 + i * 2 + o] = 0.3f * ftanh(acc);
        } else {
            float t   = ftanh(acc);
            float lsv = -5.0f + 3.5f * (t + 1.0f);
            out[43008 + b * 42 + i * 2 + (o - 2)] = __expf(lsv);
        }
    }
}

extern "C" void kernel_launch(void* const* d_in, const int* in_sizes, int n_in,
                              void* d_out, int out_size, void* d_ws, size_t ws_size,
                              hipStream_t stream) {
    (void)in_sizes; (void)n_in; (void)out_size;
    const float* state = (const float*)d_in[0];
    const float* ts    = (const float*)d_in[1];
    const float* emb   = (const float*)d_in[2];
    const float* We    = (const float*)d_in[3];
    const float* be    = (const float*)d_in[4];
    const float* Ws1   = (const float*)d_in[5];
    const float* bs1   = (const float*)d_in[6];
    const float* Ws2   = (const float*)d_in[7];
    const float* bs2   = (const float*)d_in[8];
    const float* Wm1   = (const float*)d_in[9];
    const float* bm1   = (const float*)d_in[10];
    const float* Wm2   = (const float*)d_in[11];
    const float* bm2   = (const float*)d_in[12];
    const float* Wa1   = (const float*)d_in[13];
    const float* ba1   = (const float*)d_in[14];
    const float* Wa2   = (const float*)d_in[15];
    const float* ba2   = (const float*)d_in[16];
    float* outp = (float*)d_out;

    float*  fe3 = (float*)d_ws;
    __bf16* w2s = (__bf16*)((char*)d_ws + 1024);
    __bf16* wdt = (__bf16*)((char*)d_ws + 33792);
    __bf16* wbt = (__bf16*)((char*)d_ws + 82944);
    __bf16* wst = (__bf16*)((char*)d_ws + 132096);
    __bf16* wat = (__bf16*)((char*)d_ws + 164864);
    const size_t need1 = 132096, need2 = 197632;
    const int level = (ws_size >= need2) ? 2 : ((ws_size >= need1) ? 1 : 0);

    setup_kernel<<<dim3(49), dim3(256), 0, stream>>>(emb, We, be, Wm2, Wm1, Ws2, Wa1,
                                                     fe3, w2s, wdt, wbt, wst, wat, level);
    if (level == 2)
        actor_kernel<2><<<dim3(1024), dim3(256), 0, stream>>>(
            state, ts, Ws1, bs1, Ws2, bs2, Wm1, bm1, Wm2, bm2,
            Wa1, ba1, Wa2, ba2, fe3, w2s, wdt, wbt, wst, wat, outp);
    else if (level == 1)
        actor_kernel<1><<<dim3(1024), dim3(256), 0, stream>>>(
            state, ts, Ws1, bs1, Ws2, bs2, Wm1, bm1, Wm2, bm2,
            Wa1, ba1, Wa2, ba2, fe3, w2s, wdt, wbt, wst, wat, outp);
    else
        actor_kernel<0><<<dim3(1024), dim3(256), 0, stream>>>(
            state, ts, Ws1, bs1, Ws2, bs2, Wm1, bm1, Wm2, bm2,
            Wa1, ba1, Wa2, ba2, fe3, w2s, wdt, wbt, wst, wat, outp);
}

// Round 15
// 67.085 us; speedup vs baseline: 1.4468x; 1.1489x over previous
//
#include <hip/hip_runtime.h>
#include <hip/hip_bf16.h>

#define NOBJ 21

typedef __bf16 bf16x8 __attribute__((ext_vector_type(8)));
typedef float f32x16 __attribute__((ext_vector_type(16)));
typedef float f32x4  __attribute__((ext_vector_type(4)));

#define PRESCALE 2.8853900817779268f   // 2*log2(e)

__device__ __forceinline__ float ftanh(float x) {
    float e = __builtin_amdgcn_exp2f(x * PRESCALE);
    float r = __builtin_amdgcn_rcpf(e + 1.0f);
    return __builtin_fmaf(-2.0f, r, 1.0f);
}
__device__ __forceinline__ float ftanh_pre(float xp) {
    float e = __builtin_amdgcn_exp2f(xp);
    float r = __builtin_amdgcn_rcpf(e + 1.0f);
    return __builtin_fmaf(-2.0f, r, 1.0f);
}

// ---------------- workspace layout ----------------
// fe3 @0 (1024) | w2s @1024 (32768) | wdt @33792 (49152) | wbt @82944 (49152)
// wst @132096 (32768) | wat @164864 (32768) | w2t @197632 (32768)  total 230400
// w2s: Wm2 16x16x32 B-frags (level-2 fallback path)
// w2t: Wm2 32x32x16 B-frags: fi=(ct*8+ks)*64+lane,
//      elem e = Wm2[ks*16+(lane>>5)*8+e][ct*32+(lane&31)]
// wdt/wbt/wst/wat: 32x32x16 B-frags: col n = ct*32+(lane&31), k = ks*16+(lane>>5)*8+e
__global__ void setup_kernel(const float* __restrict__ emb, const float* __restrict__ We,
                             const float* __restrict__ be, const float* __restrict__ Wm2,
                             const float* __restrict__ Wm1, const float* __restrict__ Ws2,
                             const float* __restrict__ Wa1,
                             float* __restrict__ fe3, __bf16* __restrict__ w2s,
                             __bf16* __restrict__ wdt, __bf16* __restrict__ wbt,
                             __bf16* __restrict__ wst, __bf16* __restrict__ wat,
                             __bf16* __restrict__ w2t, int level) {
    int t = threadIdx.x;
    if (blockIdx.x == 56) {
        if (t < 192) {
            int cc = t >> 6, e = t & 63;
            float acc = be[e];
            for (int k = 0; k < 64; ++k)
                acc += ftanh(emb[cc * 64 + k]) * We[k * 64 + e];
            fe3[t] = ftanh(acc);
        }
        return;
    }
    int fid = blockIdx.x * 256 + t;   // 0..14335
    if (fid < 2048) {                 // w2s (16x16 frags)
        if (level < 1) return;
        int nt = fid >> 8, kf = (fid >> 6) & 3, ln = fid & 63;
        int n  = nt * 16 + (ln & 15);
        int k0 = kf * 32 + ((ln >> 4) & 3) * 8;
        bf16x8 v;
        #pragma unroll
        for (int e = 0; e < 8; ++e) v[e] = (__bf16)Wm2[(k0 + e) * 128 + n];
        *reinterpret_cast<bf16x8*>(&w2s[fid * 8]) = v;
    } else if (fid < 5120) {          // wdt (K=192)
        if (level < 1) return;
        int q = fid - 2048;
        int ct = q / 768, r = q % 768, ks = r >> 6, ln = r & 63;
        int n = ct * 32 + (ln & 31), k0 = ks * 16 + (ln >> 5) * 8;
        bf16x8 v;
        #pragma unroll
        for (int e = 0; e < 8; ++e)
            v[e] = (__bf16)(Wm1[(k0 + e) * 128 + n] - Wm1[(192 + k0 + e) * 128 + n]);
        *reinterpret_cast<bf16x8*>(&wdt[q * 8]) = v;
    } else if (fid < 8192) {          // wbt (K=192)
        if (level < 1) return;
        int q = fid - 5120;
        int ct = q / 768, r = q % 768, ks = r >> 6, ln = r & 63;
        int n = ct * 32 + (ln & 31), k0 = ks * 16 + (ln >> 5) * 8;
        bf16x8 v;
        #pragma unroll
        for (int e = 0; e < 8; ++e) v[e] = (__bf16)Wm1[(192 + k0 + e) * 128 + n];
        *reinterpret_cast<bf16x8*>(&wbt[q * 8]) = v;
    } else if (fid < 10240) {         // wst (K=128)
        if (level < 2) return;
        int q = fid - 8192;
        int ct = q >> 9, ks = (q >> 6) & 7, ln = q & 63;
        int n = ct * 32 + (ln & 31), k0 = ks * 16 + (ln >> 5) * 8;
        bf16x8 v;
        #pragma unroll
        for (int e = 0; e < 8; ++e) v[e] = (__bf16)Ws2[(k0 + e) * 128 + n];
        *reinterpret_cast<bf16x8*>(&wst[q * 8]) = v;
    } else if (fid < 12288) {         // wat (K=128)
        if (level < 2) return;
        int q = fid - 10240;
        int ct = q >> 9, ks = (q >> 6) & 7, ln = q & 63;
        int n = ct * 32 + (ln & 31), k0 = ks * 16 + (ln >> 5) * 8;
        bf16x8 v;
        #pragma unroll
        for (int e = 0; e < 8; ++e) v[e] = (__bf16)Wa1[(k0 + e) * 128 + n];
        *reinterpret_cast<bf16x8*>(&wat[q * 8]) = v;
    } else {                          // w2t (K=128, 32x32 frags)
        if (level < 3) return;
        int q = fid - 12288;
        int ct = q >> 9, ks = (q >> 6) & 7, ln = q & 63;
        int n = ct * 32 + (ln & 31), k0 = ks * 16 + (ln >> 5) * 8;
        bf16x8 v;
        #pragma unroll
        for (int e = 0; e < 8; ++e) v[e] = (__bf16)Wm2[(k0 + e) * 128 + n];
        *reinterpret_cast<bf16x8*>(&w2t[q * 8]) = v;
    }
}

// f32 LDS 16B-chunk XOR swizzle (row-major [*][128] f32)
__device__ __forceinline__ int uvswz(int row, int k) {
    return row * 128 + (((k >> 2) ^ (row & 15)) << 2) + (k & 3);
}
// bf16 LDS 16B-chunk XOR swizzle (row-major [*][128] bf16)
__device__ __forceinline__ int bswz(int row, int k) {
    return row * 128 + (((k >> 3) ^ (row & 15)) << 3) + (k & 7);
}

// LDS layout (40448 B):
//   @0     hL bf16 swz [32][128] | uL f32 swz [21][128] (step3+) | a1L f32 (phase3+)
//   @10752 vL f32 swz [21][128] | spl/cat overlay (steps 0-1)
//   @21504 fL bf16 swz [21][256] (steps2-3) | mxK u32 [21][128] (phase2, level3)
//   @32256 xL bf16 swz [32][128]
// NOTE: uL/vL hold PRE-SCALED (x2log2e) values; consumed only by phase-2 tanh.
#define SMEM_SZ 40448

template<int WS>
__global__ __launch_bounds__(256, 2)
void actor_kernel(const float* __restrict__ state, const float* __restrict__ ts,
                  const float* __restrict__ Ws1, const float* __restrict__ bs1,
                  const float* __restrict__ Ws2, const float* __restrict__ bs2,
                  const float* __restrict__ Wm1, const float* __restrict__ bm1,
                  const float* __restrict__ Wm2, const float* __restrict__ bm2,
                  const float* __restrict__ Wa1, const float* __restrict__ ba1,
                  const float* __restrict__ Wa2, const float* __restrict__ ba2,
                  const float* __restrict__ fe3, const __bf16* __restrict__ w2s,
                  const __bf16* __restrict__ wdt, const __bf16* __restrict__ wbt,
                  const __bf16* __restrict__ wst, const __bf16* __restrict__ wat,
                  const __bf16* __restrict__ w2t, float* __restrict__ out) {
    __shared__ __align__(16) unsigned char smem[SMEM_SZ];
    __bf16* hL  = (__bf16*)(smem);
    float*  uL  = (float*)(smem);
    float*  a1L = (float*)(smem);
    float*  vL  = (float*)(smem + 10752);
    float*  spl = (float*)(smem + 10752);
    int*    catl= (int*)(smem + 10752 + 336);
    __bf16* fL  = (__bf16*)(smem + 21504);
    unsigned int* mxK = (unsigned int*)(smem + 21504);
    __bf16* xL  = (__bf16*)(smem + 32256);

    const int b   = blockIdx.x;
    const int tid = threadIdx.x;
    const int c   = tid & 127;
    const int half= tid >> 7;
    const int i0  = half ? 11 : 0;
    const int NI  = half ? (NOBJ - 11) : 11;
    const int lane = tid & 63;
    const int wave = tid >> 6;
    const int rowA = lane & 31;
    const int hi   = lane >> 5;

    // ---- step 0 ----
    if (tid < NOBJ * 4) {
        int i = tid >> 2, m = tid & 3;
        float v;
        if (m < 2) v = state[b * 63 + i * 3 + m];
        else       v = ftanh(ts[(b * NOBJ + i) * 2 + (m - 2)]);
        spl[tid] = v;
    }
    if (tid >= 128 && tid < 128 + NOBJ) {
        int i = tid - 128;
        catl[i] = (int)state[b * 63 + i * 3 + 2];
    }
    __syncthreads();

    // ---- step 1 ----
    {
        float b1 = bs1[c];
        float w0 = Ws1[0 * 128 + c], w1 = Ws1[1 * 128 + c];
        float w2 = Ws1[2 * 128 + c], w3 = Ws1[3 * 128 + c];
        for (int g = 0; g < NI; ++g) {
            int i = i0 + g;
            float acc = b1 + spl[i*4+0]*w0 + spl[i*4+1]*w1 + spl[i*4+2]*w2 + spl[i*4+3]*w3;
            hL[bswz(i, c)] = (__bf16)ftanh(acc);
        }
    }
    __syncthreads();

    // ---- step 2 ----
    if constexpr (WS >= 2) {
        const int cN = wave * 32 + rowA;
        f32x16 accS;
        #pragma unroll
        for (int r = 0; r < 16; ++r) accS[r] = 0.f;
        #pragma unroll
        for (int ks = 0; ks < 8; ++ks) {
            int ch = 2 * ks + hi;
            bf16x8 a = *(const bf16x8*)&hL[rowA * 128 + ((ch ^ (rowA & 15)) << 3)];
            bf16x8 bb = *(const bf16x8*)&wst[((wave * 8 + ks) * 64 + lane) * 8];
            accS = __builtin_amdgcn_mfma_f32_32x32x16_bf16(a, bb, accS, 0, 0, 0);
        }
        float b2 = bs2[cN];
        #pragma unroll
        for (int r = 0; r < 16; ++r) {
            int j = (r & 3) + 8 * (r >> 2) + 4 * hi;
            if (j < NOBJ)
                fL[j * 256 + (((cN >> 3) ^ (j & 15)) << 3) + (cN & 7)] = (__bf16)ftanh(accS[r] + b2);
        }
    } else {
        float acc[11];
        #pragma unroll
        for (int g = 0; g < 11; ++g) acc[g] = 0.f;
        const unsigned int* hrow = (const unsigned int*)hL;
        for (int k2 = 0; k2 < 64; ++k2) {
            float w0 = Ws2[(2 * k2) * 128 + c];
            float w1 = Ws2[(2 * k2 + 1) * 128 + c];
            #pragma unroll
            for (int g = 0; g < 11; ++g) {
                if (g < NI) {
                    int i = i0 + g;
                    unsigned int pr = hrow[i * 64 + (((k2 >> 2) ^ (i & 15)) << 2) + (k2 & 3)];
                    float lo = __uint_as_float(pr << 16);
                    float hh = __uint_as_float(pr & 0xffff0000u);
                    acc[g] = __builtin_fmaf(hh, w1, __builtin_fmaf(lo, w0, acc[g]));
                }
            }
        }
        float b2 = bs2[c];
        for (int g = 0; g < NI; ++g) {
            int i = i0 + g;
            fL[i * 256 + (((c >> 3) ^ (i & 15)) << 3) + (c & 7)] = (__bf16)ftanh(acc[g] + b2);
        }
    }
    for (int idx = tid; idx < NOBJ * 64; idx += 256) {
        int i = idx >> 6, e = idx & 63;
        fL[i * 256 + ((((16 + (e >> 3)) ^ (i & 15))) << 3) + (e & 7)] = (__bf16)fe3[catl[i] * 64 + e];
    }
    __syncthreads();

    // ---- step 3: u,v (PRE-SCALED) via 32x32 MFMA ----
    if constexpr (WS >= 1) {
        const int cN = wave * 32 + rowA;
        const int jcA = rowA < NOBJ ? rowA : NOBJ - 1;
        f32x16 accU, accV;
        #pragma unroll
        for (int r = 0; r < 16; ++r) { accU[r] = 0.f; accV[r] = 0.f; }
        #pragma unroll
        for (int ks = 0; ks < 12; ++ks) {
            int ch = 2 * ks + hi;
            bf16x8 a = *(const bf16x8*)&fL[jcA * 256 + ((ch ^ (jcA & 15)) << 3)];
            int fi = (wave * 12 + ks) * 64 + lane;
            bf16x8 bu = *(const bf16x8*)&wdt[fi * 8];
            bf16x8 bv = *(const bf16x8*)&wbt[fi * 8];
            accU = __builtin_amdgcn_mfma_f32_32x32x16_bf16(a, bu, accU, 0, 0, 0);
            accV = __builtin_amdgcn_mfma_f32_32x32x16_bf16(a, bv, accV, 0, 0, 0);
        }
        float b1s = bm1[cN] * PRESCALE;
        #pragma unroll
        for (int r = 0; r < 16; ++r) {
            int j = (r & 3) + 8 * (r >> 2) + 4 * hi;
            if (j < NOBJ) {
                uL[uvswz(j, cN)] = __builtin_fmaf(accU[r], PRESCALE, b1s);
                vL[uvswz(j, cN)] = accV[r] * PRESCALE;
            }
        }
    } else {
        float ua[11], va[11];
        #pragma unroll
        for (int g = 0; g < 11; ++g) { ua[g] = 0.f; va[g] = 0.f; }
        const unsigned int* frow = (const unsigned int*)fL;
        for (int k2 = 0; k2 < 96; ++k2) {
            int k = 2 * k2;
            float wt0 = Wm1[k * 128 + c],         wt1 = Wm1[(k + 1) * 128 + c];
            float wb0 = Wm1[(192 + k) * 128 + c], wb1 = Wm1[(193 + k) * 128 + c];
            float wd0 = wt0 - wb0, wd1 = wt1 - wb1;
            #pragma unroll
            for (int g = 0; g < 11; ++g) {
                if (g < NI) {
                    int i = i0 + g;
                    unsigned int pr = frow[i * 128 + (((k2 >> 2) ^ (i & 15)) << 2) + (k2 & 3)];
                    float lo = __uint_as_float(pr << 16);
                    float hh = __uint_as_float(pr & 0xffff0000u);
                    ua[g] = __builtin_fmaf(hh, wd1, __builtin_fmaf(lo, wd0, ua[g]));
                    va[g] = __builtin_fmaf(hh, wb1, __builtin_fmaf(lo, wb0, va[g]));
                }
            }
        }
        float b1 = bm1[c];
        for (int g = 0; g < NI; ++g) {
            uL[uvswz(i0 + g, c)] = (ua[g] + b1) * PRESCALE;
            vL[uvswz(i0 + g, c)] = va[g] * PRESCALE;
        }
    }
    __syncthreads();

    if constexpr (WS == 3) {
        // ---- phase 2 (packed pairs): 441 (i,j) pairs in 14 tiles of 32 rows ----
        // fL is dead; mxK overlays it. Init keys to 0 (below all real keys).
        for (int idx = tid; idx < NOBJ * 128; idx += 256) mxK[idx] = 0u;
        __syncthreads();

        for (int t = wave; t < 14; t += 4) {
            int pairA = t * 32 + rowA;
            int pac = pairA > 440 ? 440 : pairA;
            int iA = (pac * 3121) >> 16;       // exact /21 for pac<448
            int jA = pac - iA * 21;
            bf16x8 afr[8];
            #pragma unroll
            for (int ks = 0; ks < 8; ++ks) {
                int c0 = ks * 4 + hi * 2;
                f32x4 uu0 = *(const f32x4*)&uL[iA * 128 + (((c0)     ^ (iA & 15)) << 2)];
                f32x4 uu1 = *(const f32x4*)&uL[iA * 128 + (((c0 + 1) ^ (iA & 15)) << 2)];
                f32x4 vv0 = *(const f32x4*)&vL[jA * 128 + (((c0)     ^ (jA & 15)) << 2)];
                f32x4 vv1 = *(const f32x4*)&vL[jA * 128 + (((c0 + 1) ^ (jA & 15)) << 2)];
                bf16x8 a;
                #pragma unroll
                for (int e = 0; e < 4; ++e) {
                    a[e]     = (__bf16)ftanh_pre(uu0[e] + vv0[e]);
                    a[4 + e] = (__bf16)ftanh_pre(uu1[e] + vv1[e]);
                }
                afr[ks] = a;
            }
            // per-D-row (ct-invariant) pair -> (i, j!=i valid) masks
            int irow[16]; int jne[16];
            #pragma unroll
            for (int r = 0; r < 16; ++r) {
                int rp = (r & 3) + 8 * (r >> 2) + 4 * hi;
                int pr = t * 32 + rp;
                int ir = (pr * 3121) >> 16;
                irow[r] = ir;
                jne[r] = (pr < 441) && (pr - ir * 21 != ir);
            }
            #pragma unroll
            for (int ct = 0; ct < 4; ++ct) {
                f32x16 acc;
                #pragma unroll
                for (int r = 0; r < 16; ++r) acc[r] = 0.f;
                __builtin_amdgcn_s_setprio(1);
                #pragma unroll
                for (int ks = 0; ks < 8; ++ks) {
                    bf16x8 bb = *(const bf16x8*)&w2t[((ct * 8 + ks) * 64 + lane) * 8];
                    acc = __builtin_amdgcn_mfma_f32_32x32x16_bf16(afr[ks], bb, acc, 0, 0, 0);
                }
                __builtin_amdgcn_s_setprio(0);
                int colb = ct * 32 + rowA;
                #pragma unroll
                for (int r = 0; r < 16; ++r) {
                    if (jne[r]) {
                        unsigned int u = __float_as_uint(acc[r]);
                        unsigned int key = (u & 0x80000000u) ? ~u : (u | 0x80000000u);
                        atomicMax(&mxK[irow[r] * 128 + colb], key);
                    }
                }
            }
        }
        __syncthreads();
        // finalize: x = tanh(max + bm2)
        for (int idx = tid; idx < NOBJ * 128; idx += 256) {
            int i = idx >> 7, n = idx & 127;
            unsigned int k = mxK[idx];
            unsigned int u = (k & 0x80000000u) ? (k & 0x7fffffffu) : ~k;
            xL[bswz(i, n)] = (__bf16)ftanh(__uint_as_float(u) + bm2[n]);
        }
        __syncthreads();
    } else {
        // ---- phase 2 (16x16 per-i path) ----
        const int l15 = lane & 15;
        const int l4  = (lane >> 4) & 3;
        const int j1c = (16 + l15) < NOBJ ? (16 + l15) : NOBJ - 1;
        float bm2v[8];
        #pragma unroll
        for (int nt = 0; nt < 8; ++nt) bm2v[nt] = bm2[nt * 16 + l15];

        for (int i = wave; i < NOBJ; i += 4) {
            bf16x8 A0[4], A1[4];
            #pragma unroll
            for (int kf = 0; kf < 4; ++kf) {
                int c0 = kf * 8 + l4 * 2;
                f32x4 u0  = *(const f32x4*)&uL[i * 128 + (((c0)     ^ (i & 15)) << 2)];
                f32x4 u1  = *(const f32x4*)&uL[i * 128 + (((c0 + 1) ^ (i & 15)) << 2)];
                f32x4 va0 = *(const f32x4*)&vL[l15 * 128 + (((c0)     ^ l15) << 2)];
                f32x4 va1 = *(const f32x4*)&vL[l15 * 128 + (((c0 + 1) ^ l15) << 2)];
                f32x4 vb0 = *(const f32x4*)&vL[j1c * 128 + (((c0)     ^ (j1c & 15)) << 2)];
                f32x4 vb1 = *(const f32x4*)&vL[j1c * 128 + (((c0 + 1) ^ (j1c & 15)) << 2)];
                bf16x8 a0f, a1f;
                #pragma unroll
                for (int e = 0; e < 4; ++e) {
                    a0f[e]     = (__bf16)ftanh_pre(u0[e] + va0[e]);
                    a0f[4 + e] = (__bf16)ftanh_pre(u1[e] + va1[e]);
                    a1f[e]     = (__bf16)ftanh_pre(u0[e] + vb0[e]);
                    a1f[4 + e] = (__bf16)ftanh_pre(u1[e] + vb1[e]);
                }
                A0[kf] = a0f; A1[kf] = a1f;
            }
            __builtin_amdgcn_s_setprio(1);
            #pragma unroll
            for (int nt = 0; nt < 8; ++nt) {
                f32x4 c0a, c1a;
                #pragma unroll
                for (int r = 0; r < 4; ++r) { c0a[r] = 0.f; c1a[r] = 0.f; }
                #pragma unroll
                for (int kf = 0; kf < 4; ++kf) {
                    bf16x8 bb;
                    if constexpr (WS >= 1) {
                        bb = *(const bf16x8*)&w2s[((nt * 4 + kf) * 64 + lane) * 8];
                    } else {
                        int k0 = kf * 32 + l4 * 8;
                        #pragma unroll
                        for (int e = 0; e < 8; ++e)
                            bb[e] = (__bf16)Wm2[(k0 + e) * 128 + nt * 16 + l15];
                    }
                    c0a = __builtin_amdgcn_mfma_f32_16x16x32_bf16(A0[kf], bb, c0a, 0, 0, 0);
                    c1a = __builtin_amdgcn_mfma_f32_16x16x32_bf16(A1[kf], bb, c1a, 0, 0, 0);
                }
                float m = -INFINITY;
                #pragma unroll
                for (int r = 0; r < 4; ++r) {
                    int j = l4 * 4 + r;
                    if (j != i) m = fmaxf(m, c0a[r]);
                }
                #pragma unroll
                for (int r = 0; r < 4; ++r) {
                    int j = 16 + l4 * 4 + r;
                    if (j < NOBJ && j != i) m = fmaxf(m, c1a[r]);
                }
                m = fmaxf(m, __shfl_xor(m, 16));
                m = fmaxf(m, __shfl_xor(m, 32));
                if (lane < 16) xL[bswz(i, nt * 16 + l15)] = (__bf16)ftanh(m + bm2v[nt]);
            }
            __builtin_amdgcn_s_setprio(0);
        }
        __syncthreads();
    }

    // ---- phase 3: a1 = tanh(x @ Wa1 + ba1) -> f32 a1L (overlays uL) ----
    if constexpr (WS >= 2) {
        const int cN = wave * 32 + rowA;
        f32x16 accP;
        #pragma unroll
        for (int r = 0; r < 16; ++r) accP[r] = 0.f;
        #pragma unroll
        for (int ks = 0; ks < 8; ++ks) {
            int ch = 2 * ks + hi;
            bf16x8 a = *(const bf16x8*)&xL[rowA * 128 + ((ch ^ (rowA & 15)) << 3)];
            bf16x8 bb = *(const bf16x8*)&wat[((wave * 8 + ks) * 64 + lane) * 8];
            accP = __builtin_amdgcn_mfma_f32_32x32x16_bf16(a, bb, accP, 0, 0, 0);
        }
        float b1 = ba1[cN];
        __syncthreads();
        #pragma unroll
        for (int r = 0; r < 16; ++r) {
            int j = (r & 3) + 8 * (r >> 2) + 4 * hi;
            if (j < NOBJ) a1L[j * 128 + cN] = ftanh(accP[r] + b1);
        }
    } else {
        float acc[11];
        #pragma unroll
        for (int g = 0; g < 11; ++g) acc[g] = 0.f;
        const unsigned int* xrow = (const unsigned int*)xL;
        for (int k2 = 0; k2 < 64; ++k2) {
            float w0 = Wa1[(2 * k2) * 128 + c];
            float w1 = Wa1[(2 * k2 + 1) * 128 + c];
            #pragma unroll
            for (int g = 0; g < 11; ++g) {
                if (g < NI) {
                    int i = i0 + g;
                    unsigned int pr = xrow[i * 64 + (((k2 >> 2) ^ (i & 15)) << 2) + (k2 & 3)];
                    float lo = __uint_as_float(pr << 16);
                    float hh = __uint_as_float(pr & 0xffff0000u);
                    acc[g] = __builtin_fmaf(hh, w1, __builtin_fmaf(lo, w0, acc[g]));
                }
            }
        }
        float b1 = ba1[c];
        __syncthreads();
        for (int g = 0; g < NI; ++g)
            a1L[(i0 + g) * 128 + c] = ftanh(acc[g] + b1);
    }
    __syncthreads();

    // ---- head ----
    if (tid < NOBJ * 4) {
        int i = tid >> 2, o = tid & 3;
        float ac0 = ba2[o], ac1 = 0.f, ac2 = 0.f, ac3 = 0.f;
        for (int k4 = 0; k4 < 32; ++k4) {
            int kr = (k4 + i) & 31;
            f32x4 av = *(const f32x4*)&a1L[i * 128 + kr * 4];
            ac0 = __builtin_fmaf(av[0], Wa2[(kr * 4 + 0) * 4 + o], ac0);
            ac1 = __builtin_fmaf(av[1], Wa2[(kr * 4 + 1) * 4 + o], ac1);
            ac2 = __builtin_fmaf(av[2], Wa2[(kr * 4 + 2) * 4 + o], ac2);
            ac3 = __builtin_fmaf(av[3], Wa2[(kr * 4 + 3) * 4 + o], ac3);
        }
        float acc = (ac0 + ac1) + (ac2 + ac3);
        if (o < 2) {
            out[b * 42 + i * 2 + o] = 0.3f * ftanh(acc);
        } else {
            float t   = ftanh(acc);
            float lsv = -5.0f + 3.5f * (t + 1.0f);
            out[43008 + b * 42 + i * 2 + (o - 2)] = __expf(lsv);
        }
    }
}

extern "C" void kernel_launch(void* const* d_in, const int* in_sizes, int n_in,
                              void* d_out, int out_size, void* d_ws, size_t ws_size,
                              hipStream_t stream) {
    (void)in_sizes; (void)n_in; (void)out_size;
    const float* state = (const float*)d_in[0];
    const float* ts    = (const float*)d_in[1];
    const float* emb   = (const float*)d_in[2];
    const float* We    = (const float*)d_in[3];
    const float* be    = (const float*)d_in[4];
    const float* Ws1   = (const float*)d_in[5];
    const float* bs1   = (const float*)d_in[6];
    const float* Ws2   = (const float*)d_in[7];
    const float* bs2   = (const float*)d_in[8];
    const float* Wm1   = (const float*)d_in[9];
    const float* bm1   = (const float*)d_in[10];
    const float* Wm2   = (const float*)d_in[11];
    const float* bm2   = (const float*)d_in[12];
    const float* Wa1   = (const float*)d_in[13];
    const float* ba1   = (const float*)d_in[14];
    const float* Wa2   = (const float*)d_in[15];
    const float* ba2   = (const float*)d_in[16];
    float* outp = (float*)d_out;

    float*  fe3 = (float*)d_ws;
    __bf16* w2s = (__bf16*)((char*)d_ws + 1024);
    __bf16* wdt = (__bf16*)((char*)d_ws + 33792);
    __bf16* wbt = (__bf16*)((char*)d_ws + 82944);
    __bf16* wst = (__bf16*)((char*)d_ws + 132096);
    __bf16* wat = (__bf16*)((char*)d_ws + 164864);
    __bf16* w2t = (__bf16*)((char*)d_ws + 197632);
    const size_t need1 = 132096, need2 = 197632, need3 = 230400;
    const int level = (ws_size >= need3) ? 3 : (ws_size >= need2) ? 2
                     : (ws_size >= need1) ? 1 : 0;

    setup_kernel<<<dim3(57), dim3(256), 0, stream>>>(emb, We, be, Wm2, Wm1, Ws2, Wa1,
                                                     fe3, w2s, wdt, wbt, wst, wat, w2t, level);
    if (level == 3)
        actor_kernel<3><<<dim3(1024), dim3(256), 0, stream>>>(
            state, ts, Ws1, bs1, Ws2, bs2, Wm1, bm1, Wm2, bm2,
            Wa1, ba1, Wa2, ba2, fe3, w2s, wdt, wbt, wst, wat, w2t, outp);
    else if (level == 2)
        actor_kernel<2><<<dim3(1024), dim3(256), 0, stream>>>(
            state, ts, Ws1, bs1, Ws2, bs2, Wm1, bm1, Wm2, bm2,
            Wa1, ba1, Wa2, ba2, fe3, w2s, wdt, wbt, wst, wat, w2t, outp);
    else if (level == 1)
        actor_kernel<1><<<dim3(1024), dim3(256), 0, stream>>>(
            state, ts, Ws1, bs1, Ws2, bs2, Wm1, bm1, Wm2, bm2,
            Wa1, ba1, Wa2, ba2, fe3, w2s, wdt, wbt, wst, wat, w2t, outp);
    else
        actor_kernel<0><<<dim3(1024), dim3(256), 0, stream>>>(
            state, ts, Ws1, bs1, Ws2, bs2, Wm1, bm1, Wm2, bm2,
            Wa1, ba1, Wa2, ba2, fe3, w2s, wdt, wbt, wst, wat, w2t, outp);
}

// Round 16
// 61.000 us; speedup vs baseline: 1.5911x; 1.0998x over previous
//
#include <hip/hip_runtime.h>
#include <hip/hip_bf16.h>

#define NOBJ 21

typedef __bf16 bf16x8 __attribute__((ext_vector_type(8)));
typedef float f32x16 __attribute__((ext_vector_type(16)));
typedef float f32x4  __attribute__((ext_vector_type(4)));

#define PRESCALE 2.8853900817779268f   // 2*log2(e)

__device__ __forceinline__ float ftanh(float x) {
    float e = __builtin_amdgcn_exp2f(x * PRESCALE);
    float r = __builtin_amdgcn_rcpf(e + 1.0f);
    return __builtin_fmaf(-2.0f, r, 1.0f);
}
__device__ __forceinline__ float ftanh_pre(float xp) {
    float e = __builtin_amdgcn_exp2f(xp);
    float r = __builtin_amdgcn_rcpf(e + 1.0f);
    return __builtin_fmaf(-2.0f, r, 1.0f);
}

// ---------------- workspace layout ----------------
// fe3 @0 (1024) | w2s @1024 (32768) | wdt @33792 (49152) | wbt @82944 (49152)
// wst @132096 (32768) | wat @164864 (32768)   total 197632
// w2s: Wm2 16x16x32 B-frags: fi=(nt*4+kf)*64+lane,
//      elem e = Wm2[kf*32+((lane>>4)&3)*8+e][nt*16+(lane&15)]
// wdt/wbt/wst/wat: 32x32x16 B-frags: col n = ct*32+(lane&31), k = ks*16+(lane>>5)*8+e
__global__ void setup_kernel(const float* __restrict__ emb, const float* __restrict__ We,
                             const float* __restrict__ be, const float* __restrict__ Wm2,
                             const float* __restrict__ Wm1, const float* __restrict__ Ws2,
                             const float* __restrict__ Wa1,
                             float* __restrict__ fe3, __bf16* __restrict__ w2s,
                             __bf16* __restrict__ wdt, __bf16* __restrict__ wbt,
                             __bf16* __restrict__ wst, __bf16* __restrict__ wat,
                             int level) {
    int t = threadIdx.x;
    if (blockIdx.x == 48) {
        if (t < 192) {
            int cc = t >> 6, e = t & 63;
            float acc = be[e];
            for (int k = 0; k < 64; ++k)
                acc += ftanh(emb[cc * 64 + k]) * We[k * 64 + e];
            fe3[t] = ftanh(acc);
        }
        return;
    }
    int fid = blockIdx.x * 256 + t;   // 0..12287
    if (fid < 2048) {                 // w2s (16x16 frags)
        if (level < 1) return;
        int nt = fid >> 8, kf = (fid >> 6) & 3, ln = fid & 63;
        int n  = nt * 16 + (ln & 15);
        int k0 = kf * 32 + ((ln >> 4) & 3) * 8;
        bf16x8 v;
        #pragma unroll
        for (int e = 0; e < 8; ++e) v[e] = (__bf16)Wm2[(k0 + e) * 128 + n];
        *reinterpret_cast<bf16x8*>(&w2s[fid * 8]) = v;
    } else if (fid < 5120) {          // wdt (K=192)
        if (level < 1) return;
        int q = fid - 2048;
        int ct = q / 768, r = q % 768, ks = r >> 6, ln = r & 63;
        int n = ct * 32 + (ln & 31), k0 = ks * 16 + (ln >> 5) * 8;
        bf16x8 v;
        #pragma unroll
        for (int e = 0; e < 8; ++e)
            v[e] = (__bf16)(Wm1[(k0 + e) * 128 + n] - Wm1[(192 + k0 + e) * 128 + n]);
        *reinterpret_cast<bf16x8*>(&wdt[q * 8]) = v;
    } else if (fid < 8192) {          // wbt (K=192)
        if (level < 1) return;
        int q = fid - 5120;
        int ct = q / 768, r = q % 768, ks = r >> 6, ln = r & 63;
        int n = ct * 32 + (ln & 31), k0 = ks * 16 + (ln >> 5) * 8;
        bf16x8 v;
        #pragma unroll
        for (int e = 0; e < 8; ++e) v[e] = (__bf16)Wm1[(192 + k0 + e) * 128 + n];
        *reinterpret_cast<bf16x8*>(&wbt[q * 8]) = v;
    } else if (fid < 10240) {         // wst (K=128)
        if (level < 2) return;
        int q = fid - 8192;
        int ct = q >> 9, ks = (q >> 6) & 7, ln = q & 63;
        int n = ct * 32 + (ln & 31), k0 = ks * 16 + (ln >> 5) * 8;
        bf16x8 v;
        #pragma unroll
        for (int e = 0; e < 8; ++e) v[e] = (__bf16)Ws2[(k0 + e) * 128 + n];
        *reinterpret_cast<bf16x8*>(&wst[q * 8]) = v;
    } else {                          // wat (K=128)
        if (level < 2) return;
        int q = fid - 10240;
        int ct = q >> 9, ks = (q >> 6) & 7, ln = q & 63;
        int n = ct * 32 + (ln & 31), k0 = ks * 16 + (ln >> 5) * 8;
        bf16x8 v;
        #pragma unroll
        for (int e = 0; e < 8; ++e) v[e] = (__bf16)Wa1[(k0 + e) * 128 + n];
        *reinterpret_cast<bf16x8*>(&wat[q * 8]) = v;
    }
}

// f32 LDS 16B-chunk XOR swizzle (row-major [*][128] f32)
__device__ __forceinline__ int uvswz(int row, int k) {
    return row * 128 + (((k >> 2) ^ (row & 15)) << 2) + (k & 3);
}
// bf16 LDS 16B-chunk XOR swizzle (row-major [*][128] bf16)
__device__ __forceinline__ int bswz(int row, int k) {
    return row * 128 + (((k >> 3) ^ (row & 15)) << 3) + (k & 7);
}

// LDS layout (40448 B):
//   @0     hL bf16 swz [32][128] | uL f32 swz [21][128] (step3+) | a1L f32 (phase3+)
//   @10752 vL f32 swz [21][128] | spl/cat overlay (steps 0-1)
//   @21504 fL bf16 swz [21][256] (steps2-3) | mxK u32 [21][128] (phase2, WS3)
//   @32256 xL bf16 swz [32][128]
// NOTE: uL/vL hold PRE-SCALED (x2log2e) values; consumed only by phase-2 tanh.
#define SMEM_SZ 40448

template<int WS>
__global__ __launch_bounds__(256, 2)
void actor_kernel(const float* __restrict__ state, const float* __restrict__ ts,
                  const float* __restrict__ Ws1, const float* __restrict__ bs1,
                  const float* __restrict__ Ws2, const float* __restrict__ bs2,
                  const float* __restrict__ Wm1, const float* __restrict__ bm1,
                  const float* __restrict__ Wm2, const float* __restrict__ bm2,
                  const float* __restrict__ Wa1, const float* __restrict__ ba1,
                  const float* __restrict__ Wa2, const float* __restrict__ ba2,
                  const float* __restrict__ fe3, const __bf16* __restrict__ w2s,
                  const __bf16* __restrict__ wdt, const __bf16* __restrict__ wbt,
                  const __bf16* __restrict__ wst, const __bf16* __restrict__ wat,
                  float* __restrict__ out) {
    __shared__ __align__(16) unsigned char smem[SMEM_SZ];
    __bf16* hL  = (__bf16*)(smem);
    float*  uL  = (float*)(smem);
    float*  a1L = (float*)(smem);
    float*  vL  = (float*)(smem + 10752);
    float*  spl = (float*)(smem + 10752);
    int*    catl= (int*)(smem + 10752 + 336);
    __bf16* fL  = (__bf16*)(smem + 21504);
    unsigned int* mxK = (unsigned int*)(smem + 21504);
    __bf16* xL  = (__bf16*)(smem + 32256);

    const int b   = blockIdx.x;
    const int tid = threadIdx.x;
    const int c   = tid & 127;
    const int half= tid >> 7;
    const int i0  = half ? 11 : 0;
    const int NI  = half ? (NOBJ - 11) : 11;
    const int lane = tid & 63;
    const int wave = tid >> 6;
    const int rowA = lane & 31;
    const int hi   = lane >> 5;

    // ---- step 0 ----
    if (tid < NOBJ * 4) {
        int i = tid >> 2, m = tid & 3;
        float v;
        if (m < 2) v = state[b * 63 + i * 3 + m];
        else       v = ftanh(ts[(b * NOBJ + i) * 2 + (m - 2)]);
        spl[tid] = v;
    }
    if (tid >= 128 && tid < 128 + NOBJ) {
        int i = tid - 128;
        catl[i] = (int)state[b * 63 + i * 3 + 2];
    }
    __syncthreads();

    // ---- step 1 ----
    {
        float b1 = bs1[c];
        float w0 = Ws1[0 * 128 + c], w1 = Ws1[1 * 128 + c];
        float w2 = Ws1[2 * 128 + c], w3 = Ws1[3 * 128 + c];
        for (int g = 0; g < NI; ++g) {
            int i = i0 + g;
            float acc = b1 + spl[i*4+0]*w0 + spl[i*4+1]*w1 + spl[i*4+2]*w2 + spl[i*4+3]*w3;
            hL[bswz(i, c)] = (__bf16)ftanh(acc);
        }
    }
    __syncthreads();

    // ---- step 2 ----
    if constexpr (WS >= 2) {
        const int cN = wave * 32 + rowA;
        f32x16 accS;
        #pragma unroll
        for (int r = 0; r < 16; ++r) accS[r] = 0.f;
        #pragma unroll
        for (int ks = 0; ks < 8; ++ks) {
            int ch = 2 * ks + hi;
            bf16x8 a = *(const bf16x8*)&hL[rowA * 128 + ((ch ^ (rowA & 15)) << 3)];
            bf16x8 bb = *(const bf16x8*)&wst[((wave * 8 + ks) * 64 + lane) * 8];
            accS = __builtin_amdgcn_mfma_f32_32x32x16_bf16(a, bb, accS, 0, 0, 0);
        }
        float b2 = bs2[cN];
        #pragma unroll
        for (int r = 0; r < 16; ++r) {
            int j = (r & 3) + 8 * (r >> 2) + 4 * hi;
            if (j < NOBJ)
                fL[j * 256 + (((cN >> 3) ^ (j & 15)) << 3) + (cN & 7)] = (__bf16)ftanh(accS[r] + b2);
        }
    } else {
        float acc[11];
        #pragma unroll
        for (int g = 0; g < 11; ++g) acc[g] = 0.f;
        const unsigned int* hrow = (const unsigned int*)hL;
        for (int k2 = 0; k2 < 64; ++k2) {
            float w0 = Ws2[(2 * k2) * 128 + c];
            float w1 = Ws2[(2 * k2 + 1) * 128 + c];
            #pragma unroll
            for (int g = 0; g < 11; ++g) {
                if (g < NI) {
                    int i = i0 + g;
                    unsigned int pr = hrow[i * 64 + (((k2 >> 2) ^ (i & 15)) << 2) + (k2 & 3)];
                    float lo = __uint_as_float(pr << 16);
                    float hh = __uint_as_float(pr & 0xffff0000u);
                    acc[g] = __builtin_fmaf(hh, w1, __builtin_fmaf(lo, w0, acc[g]));
                }
            }
        }
        float b2 = bs2[c];
        for (int g = 0; g < NI; ++g) {
            int i = i0 + g;
            fL[i * 256 + (((c >> 3) ^ (i & 15)) << 3) + (c & 7)] = (__bf16)ftanh(acc[g] + b2);
        }
    }
    for (int idx = tid; idx < NOBJ * 64; idx += 256) {
        int i = idx >> 6, e = idx & 63;
        fL[i * 256 + ((((16 + (e >> 3)) ^ (i & 15))) << 3) + (e & 7)] = (__bf16)fe3[catl[i] * 64 + e];
    }
    __syncthreads();

    // ---- step 3: u,v (PRE-SCALED) via 32x32 MFMA ----
    if constexpr (WS >= 1) {
        const int cN = wave * 32 + rowA;
        const int jcA = rowA < NOBJ ? rowA : NOBJ - 1;
        f32x16 accU, accV;
        #pragma unroll
        for (int r = 0; r < 16; ++r) { accU[r] = 0.f; accV[r] = 0.f; }
        #pragma unroll
        for (int ks = 0; ks < 12; ++ks) {
            int ch = 2 * ks + hi;
            bf16x8 a = *(const bf16x8*)&fL[jcA * 256 + ((ch ^ (jcA & 15)) << 3)];
            int fi = (wave * 12 + ks) * 64 + lane;
            bf16x8 bu = *(const bf16x8*)&wdt[fi * 8];
            bf16x8 bv = *(const bf16x8*)&wbt[fi * 8];
            accU = __builtin_amdgcn_mfma_f32_32x32x16_bf16(a, bu, accU, 0, 0, 0);
            accV = __builtin_amdgcn_mfma_f32_32x32x16_bf16(a, bv, accV, 0, 0, 0);
        }
        float b1s = bm1[cN] * PRESCALE;
        #pragma unroll
        for (int r = 0; r < 16; ++r) {
            int j = (r & 3) + 8 * (r >> 2) + 4 * hi;
            if (j < NOBJ) {
                uL[uvswz(j, cN)] = __builtin_fmaf(accU[r], PRESCALE, b1s);
                vL[uvswz(j, cN)] = accV[r] * PRESCALE;
            }
        }
    } else {
        float ua[11], va[11];
        #pragma unroll
        for (int g = 0; g < 11; ++g) { ua[g] = 0.f; va[g] = 0.f; }
        const unsigned int* frow = (const unsigned int*)fL;
        for (int k2 = 0; k2 < 96; ++k2) {
            int k = 2 * k2;
            float wt0 = Wm1[k * 128 + c],         wt1 = Wm1[(k + 1) * 128 + c];
            float wb0 = Wm1[(192 + k) * 128 + c], wb1 = Wm1[(193 + k) * 128 + c];
            float wd0 = wt0 - wb0, wd1 = wt1 - wb1;
            #pragma unroll
            for (int g = 0; g < 11; ++g) {
                if (g < NI) {
                    int i = i0 + g;
                    unsigned int pr = frow[i * 128 + (((k2 >> 2) ^ (i & 15)) << 2) + (k2 & 3)];
                    float lo = __uint_as_float(pr << 16);
                    float hh = __uint_as_float(pr & 0xffff0000u);
                    ua[g] = __builtin_fmaf(hh, wd1, __builtin_fmaf(lo, wd0, ua[g]));
                    va[g] = __builtin_fmaf(hh, wb1, __builtin_fmaf(lo, wb0, va[g]));
                }
            }
        }
        float b1 = bm1[c];
        for (int g = 0; g < NI; ++g) {
            uL[uvswz(i0 + g, c)] = (ua[g] + b1) * PRESCALE;
            vL[uvswz(i0 + g, c)] = va[g] * PRESCALE;
        }
    }
    __syncthreads();

    if constexpr (WS == 3) {
        // ---- phase 2 (packed 16x16): 441 pairs in 28 tiles of 16 rows, 7/wave ----
        for (int idx = tid; idx < NOBJ * 128; idx += 256) mxK[idx] = 0u;
        __syncthreads();
        const int l15 = lane & 15;
        const int l4  = (lane >> 4) & 3;

        for (int t = wave; t < 28; t += 4) {
            int pA = t * 16 + l15;
            int pac = pA > 440 ? 440 : pA;
            int iA = (pac * 3121) >> 16;       // exact /21 for pac<448
            int jA = pac - iA * 21;
            bf16x8 A[4];
            #pragma unroll
            for (int kf = 0; kf < 4; ++kf) {
                int c0 = kf * 8 + l4 * 2;
                f32x4 uu0 = *(const f32x4*)&uL[iA * 128 + (((c0)     ^ (iA & 15)) << 2)];
                f32x4 uu1 = *(const f32x4*)&uL[iA * 128 + (((c0 + 1) ^ (iA & 15)) << 2)];
                f32x4 vv0 = *(const f32x4*)&vL[jA * 128 + (((c0)     ^ (jA & 15)) << 2)];
                f32x4 vv1 = *(const f32x4*)&vL[jA * 128 + (((c0 + 1) ^ (jA & 15)) << 2)];
                bf16x8 a;
                #pragma unroll
                for (int e = 0; e < 4; ++e) {
                    a[e]     = (__bf16)ftanh_pre(uu0[e] + vv0[e]);
                    a[4 + e] = (__bf16)ftanh_pre(uu1[e] + vv1[e]);
                }
                A[kf] = a;
            }
            // D rows (ct-invariant): row = l4*4 + r
            int irow[4]; int jne[4];
            #pragma unroll
            for (int r = 0; r < 4; ++r) {
                int pr = t * 16 + l4 * 4 + r;
                int ir = (pr * 3121) >> 16;
                irow[r] = ir;
                jne[r] = (pr < 441) && (pr - ir * 21 != ir);
            }
            __builtin_amdgcn_s_setprio(1);
            #pragma unroll
            for (int nt = 0; nt < 8; ++nt) {
                f32x4 acc;
                #pragma unroll
                for (int r = 0; r < 4; ++r) acc[r] = 0.f;
                #pragma unroll
                for (int kf = 0; kf < 4; ++kf) {
                    bf16x8 bb = *(const bf16x8*)&w2s[((nt * 4 + kf) * 64 + lane) * 8];
                    acc = __builtin_amdgcn_mfma_f32_16x16x32_bf16(A[kf], bb, acc, 0, 0, 0);
                }
                int colb = nt * 16 + l15;
                #pragma unroll
                for (int r = 0; r < 4; ++r) {
                    if (jne[r]) {
                        unsigned int u = __float_as_uint(acc[r]);
                        unsigned int key = (u & 0x80000000u) ? ~u : (u | 0x80000000u);
                        atomicMax(&mxK[irow[r] * 128 + colb], key);
                    }
                }
            }
            __builtin_amdgcn_s_setprio(0);
        }
        __syncthreads();
        // finalize: x = tanh(max + bm2)
        for (int idx = tid; idx < NOBJ * 128; idx += 256) {
            int i = idx >> 7, n = idx & 127;
            unsigned int k = mxK[idx];
            unsigned int u = (k & 0x80000000u) ? (k & 0x7fffffffu) : ~k;
            xL[bswz(i, n)] = (__bf16)ftanh(__uint_as_float(u) + bm2[n]);
        }
        __syncthreads();
    } else {
        // ---- phase 2 (16x16 per-i path) ----
        const int l15 = lane & 15;
        const int l4  = (lane >> 4) & 3;
        const int j1c = (16 + l15) < NOBJ ? (16 + l15) : NOBJ - 1;
        float bm2v[8];
        #pragma unroll
        for (int nt = 0; nt < 8; ++nt) bm2v[nt] = bm2[nt * 16 + l15];

        for (int i = wave; i < NOBJ; i += 4) {
            bf16x8 A0[4], A1[4];
            #pragma unroll
            for (int kf = 0; kf < 4; ++kf) {
                int c0 = kf * 8 + l4 * 2;
                f32x4 u0  = *(const f32x4*)&uL[i * 128 + (((c0)     ^ (i & 15)) << 2)];
                f32x4 u1  = *(const f32x4*)&uL[i * 128 + (((c0 + 1) ^ (i & 15)) << 2)];
                f32x4 va0 = *(const f32x4*)&vL[l15 * 128 + (((c0)     ^ l15) << 2)];
                f32x4 va1 = *(const f32x4*)&vL[l15 * 128 + (((c0 + 1) ^ l15) << 2)];
                f32x4 vb0 = *(const f32x4*)&vL[j1c * 128 + (((c0)     ^ (j1c & 15)) << 2)];
                f32x4 vb1 = *(const f32x4*)&vL[j1c * 128 + (((c0 + 1) ^ (j1c & 15)) << 2)];
                bf16x8 a0f, a1f;
                #pragma unroll
                for (int e = 0; e < 4; ++e) {
                    a0f[e]     = (__bf16)ftanh_pre(u0[e] + va0[e]);
                    a0f[4 + e] = (__bf16)ftanh_pre(u1[e] + va1[e]);
                    a1f[e]     = (__bf16)ftanh_pre(u0[e] + vb0[e]);
                    a1f[4 + e] = (__bf16)ftanh_pre(u1[e] + vb1[e]);
                }
                A0[kf] = a0f; A1[kf] = a1f;
            }
            __builtin_amdgcn_s_setprio(1);
            #pragma unroll
            for (int nt = 0; nt < 8; ++nt) {
                f32x4 c0a, c1a;
                #pragma unroll
                for (int r = 0; r < 4; ++r) { c0a[r] = 0.f; c1a[r] = 0.f; }
                #pragma unroll
                for (int kf = 0; kf < 4; ++kf) {
                    bf16x8 bb;
                    if constexpr (WS >= 1) {
                        bb = *(const bf16x8*)&w2s[((nt * 4 + kf) * 64 + lane) * 8];
                    } else {
                        int k0 = kf * 32 + l4 * 8;
                        #pragma unroll
                        for (int e = 0; e < 8; ++e)
                            bb[e] = (__bf16)Wm2[(k0 + e) * 128 + nt * 16 + l15];
                    }
                    c0a = __builtin_amdgcn_mfma_f32_16x16x32_bf16(A0[kf], bb, c0a, 0, 0, 0);
                    c1a = __builtin_amdgcn_mfma_f32_16x16x32_bf16(A1[kf], bb, c1a, 0, 0, 0);
                }
                float m = -INFINITY;
                #pragma unroll
                for (int r = 0; r < 4; ++r) {
                    int j = l4 * 4 + r;
                    if (j != i) m = fmaxf(m, c0a[r]);
                }
                #pragma unroll
                for (int r = 0; r < 4; ++r) {
                    int j = 16 + l4 * 4 + r;
                    if (j < NOBJ && j != i) m = fmaxf(m, c1a[r]);
                }
                m = fmaxf(m, __shfl_xor(m, 16));
                m = fmaxf(m, __shfl_xor(m, 32));
                if (lane < 16) xL[bswz(i, nt * 16 + l15)] = (__bf16)ftanh(m + bm2v[nt]);
            }
            __builtin_amdgcn_s_setprio(0);
        }
        __syncthreads();
    }

    // ---- phase 3: a1 = tanh(x @ Wa1 + ba1) -> f32 a1L (overlays uL) ----
    if constexpr (WS >= 2) {
        const int cN = wave * 32 + rowA;
        f32x16 accP;
        #pragma unroll
        for (int r = 0; r < 16; ++r) accP[r] = 0.f;
        #pragma unroll
        for (int ks = 0; ks < 8; ++ks) {
            int ch = 2 * ks + hi;
            bf16x8 a = *(const bf16x8*)&xL[rowA * 128 + ((ch ^ (rowA & 15)) << 3)];
            bf16x8 bb = *(const bf16x8*)&wat[((wave * 8 + ks) * 64 + lane) * 8];
            accP = __builtin_amdgcn_mfma_f32_32x32x16_bf16(a, bb, accP, 0, 0, 0);
        }
        float b1 = ba1[cN];
        __syncthreads();
        #pragma unroll
        for (int r = 0; r < 16; ++r) {
            int j = (r & 3) + 8 * (r >> 2) + 4 * hi;
            if (j < NOBJ) a1L[j * 128 + cN] = ftanh(accP[r] + b1);
        }
    } else {
        float acc[11];
        #pragma unroll
        for (int g = 0; g < 11; ++g) acc[g] = 0.f;
        const unsigned int* xrow = (const unsigned int*)xL;
        for (int k2 = 0; k2 < 64; ++k2) {
            float w0 = Wa1[(2 * k2) * 128 + c];
            float w1 = Wa1[(2 * k2 + 1) * 128 + c];
            #pragma unroll
            for (int g = 0; g < 11; ++g) {
                if (g < NI) {
                    int i = i0 + g;
                    unsigned int pr = xrow[i * 64 + (((k2 >> 2) ^ (i & 15)) << 2) + (k2 & 3)];
                    float lo = __uint_as_float(pr << 16);
                    float hh = __uint_as_float(pr & 0xffff0000u);
                    acc[g] = __builtin_fmaf(hh, w1, __builtin_fmaf(lo, w0, acc[g]));
                }
            }
        }
        float b1 = ba1[c];
        __syncthreads();
        for (int g = 0; g < NI; ++g)
            a1L[(i0 + g) * 128 + c] = ftanh(acc[g] + b1);
    }
    __syncthreads();

    // ---- head ----
    if (tid < NOBJ * 4) {
        int i = tid >> 2, o = tid & 3;
        float ac0 = ba2[o], ac1 = 0.f, ac2 = 0.f, ac3 = 0.f;
        for (int k4 = 0; k4 < 32; ++k4) {
            int kr = (k4 + i) & 31;
            f32x4 av = *(const f32x4*)&a1L[i * 128 + kr * 4];
            ac0 = __builtin_fmaf(av[0], Wa2[(kr * 4 + 0) * 4 + o], ac0);
            ac1 = __builtin_fmaf(av[1], Wa2[(kr * 4 + 1) * 4 + o], ac1);
            ac2 = __builtin_fmaf(av[2], Wa2[(kr * 4 + 2) * 4 + o], ac2);
            ac3 = __builtin_fmaf(av[3], Wa2[(kr * 4 + 3) * 4 + o], ac3);
        }
        float acc = (ac0 + ac1) + (ac2 + ac3);
        if (o < 2) {
            out[b * 42 + i * 2 + o] = 0.3f * ftanh(acc);
        } else {
            float t   = ftanh(acc);
            float lsv = -5.0f + 3.5f * (t + 1.0f);
            out[43008 + b * 42 + i * 2 + (o - 2)] = __expf(lsv);
        }
    }
}

extern "C" void kernel_launch(void* const* d_in, const int* in_sizes, int n_in,
                              void* d_out, int out_size, void* d_ws, size_t ws_size,
                              hipStream_t stream) {
    (void)in_sizes; (void)n_in; (void)out_size;
    const float* state = (const float*)d_in[0];
    const float* ts    = (const float*)d_in[1];
    const float* emb   = (const float*)d_in[2];
    const float* We    = (const float*)d_in[3];
    const float* be    = (const float*)d_in[4];
    const float* Ws1   = (const float*)d_in[5];
    const float* bs1   = (const float*)d_in[6];
    const float* Ws2   = (const float*)d_in[7];
    const float* bs2   = (const float*)d_in[8];
    const float* Wm1   = (const float*)d_in[9];
    const float* bm1   = (const float*)d_in[10];
    const float* Wm2   = (const float*)d_in[11];
    const float* bm2   = (const float*)d_in[12];
    const float* Wa1   = (const float*)d_in[13];
    const float* ba1   = (const float*)d_in[14];
    const float* Wa2   = (const float*)d_in[15];
    const float* ba2   = (const float*)d_in[16];
    float* outp = (float*)d_out;

    float*  fe3 = (float*)d_ws;
    __bf16* w2s = (__bf16*)((char*)d_ws + 1024);
    __bf16* wdt = (__bf16*)((char*)d_ws + 33792);
    __bf16* wbt = (__bf16*)((char*)d_ws + 82944);
    __bf16* wst = (__bf16*)((char*)d_ws + 132096);
    __bf16* wat = (__bf16*)((char*)d_ws + 164864);
    const size_t need1 = 132096, need2 = 197632;
    const int slevel = (ws_size >= need2) ? 2 : (ws_size >= need1) ? 1 : 0;

    setup_kernel<<<dim3(49), dim3(256), 0, stream>>>(emb, We, be, Wm2, Wm1, Ws2, Wa1,
                                                     fe3, w2s, wdt, wbt, wst, wat, slevel);
    if (slevel == 2)
        actor_kernel<3><<<dim3(1024), dim3(256), 0, stream>>>(
            state, ts, Ws1, bs1, Ws2, bs2, Wm1, bm1, Wm2, bm2,
            Wa1, ba1, Wa2, ba2, fe3, w2s, wdt, wbt, wst, wat, outp);
    else if (slevel == 1)
        actor_kernel<1><<<dim3(1024), dim3(256), 0, stream>>>(
            state, ts, Ws1, bs1, Ws2, bs2, Wm1, bm1, Wm2, bm2,
            Wa1, ba1, Wa2, ba2, fe3, w2s, wdt, wbt, wst, wat, outp);
    else
        actor_kernel<0><<<dim3(1024), dim3(256), 0, stream>>>(
            state, ts, Ws1, bs1, Ws2, bs2, Wm1, bm1, Wm2, bm2,
            Wa1, ba1, Wa2, ba2, fe3, w2s, wdt, wbt, wst, wat, outp);
}